// Round 2
// baseline (195046.448 us; speedup 1.0000x reference)
//
#include <hip/hip_runtime.h>
#include <stdint.h>
#include <stddef.h>

#define B 16
#define T 400
#define E 768
#define PDIM 256
#define H 1024
#define ADIM 128
#define LDIM 32
#define MDIM 80

#define NBP 512   // persistent grid: 512 blocks x 256 thr; __launch_bounds__(256,2) guarantees >=2 blocks/CU co-resident

typedef unsigned short u16;
typedef __attribute__((ext_vector_type(8))) short short8v;
typedef __attribute__((ext_vector_type(4))) float float4v;

__device__ __forceinline__ float bf2f(u16 u){
  union { uint32_t i; float f; } v; v.i = ((uint32_t)u) << 16; return v.f;
}
__device__ __forceinline__ u16 f2bf(float f){
  union { float f; uint32_t i; } v; v.f = f;
  uint32_t x = v.i;
  return (u16)((x + 0x7FFFu + ((x >> 16) & 1u)) >> 16);
}
__device__ __forceinline__ float fast_sig(float x){ return 1.f/(1.f+__expf(-x)); }
__device__ __forceinline__ float fast_tanh(float x){ float e=__expf(2.f*x); return 1.f - 2.f/(e+1.f); }

// compile-time specialized loads
template<bool F32>
__device__ __forceinline__ float ld1(const void* p, size_t i){
  if constexpr(F32){ float v; __builtin_memcpy(&v, (const float*)p + i, 4); return v; }
  else { u16 h; __builtin_memcpy(&h, (const u16*)p + i, 2); return bf2f(h); }
}
template<bool F32>
__device__ __forceinline__ void ld4(const void* p, size_t i, float o[4]){
  if constexpr(F32){ __builtin_memcpy(o, (const float*)p + i, 16); }
  else {
    uint2 u; __builtin_memcpy(&u, (const u16*)p + i, 8);
    o[0]=bf2f((u16)(u.x & 0xffffu)); o[1]=bf2f((u16)(u.x >> 16));
    o[2]=bf2f((u16)(u.y & 0xffffu)); o[3]=bf2f((u16)(u.y >> 16));
  }
}
template<bool F32>
__device__ __forceinline__ void st1(void* p, size_t i, float v){
  if constexpr(F32) ((float*)p)[i] = v; else ((u16*)p)[i] = f2bf(v);
}

// ---------------- dtype detect ----------------
__global__ void k_detect(const uint32_t* __restrict__ x, int* flag){
  uint32_t w = x[threadIdx.x];
  float v = bf2f((u16)(w & 0xffffu));
  int bad = (fabsf(v) < 1e4f) ? 0 : 1;   // NaN -> bad
  __shared__ int s[256];
  s[threadIdx.x] = bad;
  __syncthreads();
  for(int st=128; st>0; st>>=1){ if(threadIdx.x<st) s[threadIdx.x]+=s[threadIdx.x+st]; __syncthreads(); }
  if(threadIdx.x==0) *flag = (s[0] >= 8) ? 1 : 0;
}

__global__ void k_zero(float* p, int n){
  int i = blockIdx.x*256 + threadIdx.x;
  if(i < n) p[i] = 0.f;
}

// ---------------- init prenet ----------------
template<bool F32>
__device__ __forceinline__ void init_prenet_body(const void* w2, const void* b1, const void* b2,
                                                 float* lstm_in){
  __shared__ float p1[PDIM];
  int j = threadIdx.x;
  p1[j] = fmaxf(ld1<F32>(b1, j), 0.f);
  __syncthreads();
  float acc = ld1<F32>(b2, j);
  for(int k=0;k<PDIM;k+=4){
    float w[4]; ld4<F32>(w2, (size_t)j*PDIM+k, w);
    acc += w[0]*p1[k]+w[1]*p1[k+1]+w[2]*p1[k+2]+w[3]*p1[k+3];
  }
  float p2 = fmaxf(acc, 0.f);
  for(int b=0;b<B;b++) lstm_in[b*H + j] = p2;
}
__global__ void k_init_prenet(const void* w2, const void* b1, const void* b2,
                              float* lstm_in, const int* dtf){
  if(*dtf) init_prenet_body<true>(w2,b1,b2,lstm_in);
  else     init_prenet_body<false>(w2,b1,b2,lstm_in);
}

// ---------------- Vh ----------------
template<bool F32>
__device__ __forceinline__ void vh_body(const void* __restrict__ x, const void* __restrict__ Vw,
                                        float* __restrict__ Vh){
  int bt = blockIdx.x;
  __shared__ float xr[E];
  for(int i=threadIdx.x;i<E;i+=128) xr[i] = ld1<F32>(x, (size_t)bt*E + i);
  __syncthreads();
  int a = threadIdx.x;
  float acc = 0.f;
#pragma unroll 4
  for(int k=0;k<E;k+=4){
    float w[4]; ld4<F32>(Vw, (size_t)a*E+k, w);
    acc += w[0]*xr[k]+w[1]*xr[k+1]+w[2]*xr[k+2]+w[3]*xr[k+3];
  }
  Vh[(size_t)bt*ADIM + a] = acc;
}
__global__ void k_vh(const void* __restrict__ x, const void* __restrict__ Vw,
                     float* __restrict__ Vh, const int* dtf){
  if(*dtf) vh_body<true>(x,Vw,Vh); else vh_body<false>(x,Vw,Vh);
}

// ------------- PostNet weight repack -------------
template<bool F32>
__device__ __forceinline__ void repack_body(const void* __restrict__ w, u16* __restrict__ wf){
  int blk = blockIdx.x;                   // kw*128 + ic*16 + ot
  int ot = blk & 15, ic = (blk >> 4) & 7, kw = blk >> 7;
  int lane = threadIdx.x;
  int o = ot*16 + (lane & 15);
  int i0 = ic*32 + (lane >> 4)*8;
  size_t dst = ((size_t)blk*64 + lane)*8;
#pragma unroll
  for(int jj=0;jj<8;jj++)
    wf[dst+jj] = f2bf(ld1<F32>(w, ((size_t)o*256 + (i0+jj))*5 + kw));
}
__global__ void k_repack(const void* w, u16* wf, const int* dtf){
  if(*dtf) repack_body<true>(w,wf); else repack_body<false>(w,wf);
}

// ------------- fused PostNet: one block per (b,t); mel lives in d_out -------------
template<bool F32>
__device__ __forceinline__ void postnet_body(
    const void* __restrict__ w1, const void* __restrict__ b1,
    const u16* __restrict__ wf2, const void* __restrict__ b2,
    const u16* __restrict__ wf3, const void* __restrict__ b3,
    const void* __restrict__ w4, const void* __restrict__ b4,
    void* __restrict__ out)
{
  __shared__ u16 YT[88*264];
  __shared__ float mell[84];
  __shared__ float w4l[256*5];
  __shared__ float red4[160];
  int bt = blockIdx.x;
  int tid = threadIdx.x;
  if(tid < 84) mell[tid] = (tid>=2 && tid<82) ? ld1<F32>(out, (size_t)bt*MDIM + tid-2) : 0.f;
  for(int i=tid;i<256*5;i+=256) w4l[i] = ld1<F32>(w4, i);
  for(int i=tid;i<4*264;i+=256){
    int r = i/264, c = i - r*264;
    int row = (r<2)? r : 80+r;
    YT[row*264 + c] = 0;
  }
  __syncthreads();
  {
    float wr[5];
#pragma unroll
    for(int q=0;q<5;q++) wr[q] = ld1<F32>(w1, tid*5+q);
    float bb = ld1<F32>(b1, tid);
    for(int m=0;m<MDIM;m++){
      float s = bb;
#pragma unroll
      for(int q=0;q<5;q++) s += wr[q]*mell[m+q];
      YT[(m+2)*264 + tid] = f2bf(fast_tanh(s));
    }
  }
  __syncthreads();
  int lane = tid & 63, wv = tid >> 6;
  int lr = lane & 15, quad = lane >> 4;
  const u16* WF[2] = {wf2, wf3};
  const void* BS[2] = {b2, b3};
#pragma unroll 1
  for(int layer=0; layer<2; layer++){
    float4v acc[4][5];
#pragma unroll
    for(int ot=0;ot<4;ot++){
      int ob = (wv*4+ot)*16 + quad*4;
#pragma unroll
      for(int mt=0;mt<5;mt++)
#pragma unroll
        for(int r=0;r<4;r++) acc[ot][mt][r] = ld1<F32>(BS[layer], ob + r);
    }
    const u16* wf = WF[layer];
    for(int kw=0;kw<5;kw++){
      for(int ic=0;ic<8;ic++){
        short8v a[4];
#pragma unroll
        for(int ot=0;ot<4;ot++){
          size_t idx = ((size_t)(kw*128 + ic*16 + (wv*4+ot))*64 + lane)*8;
          __builtin_memcpy(&a[ot], &wf[idx], 16);
        }
        short8v bfr[5];
        int ib = ic*32 + quad*8;
#pragma unroll
        for(int mt=0;mt<5;mt++){
          int row = mt*16 + lr + kw;
          __builtin_memcpy(&bfr[mt], &YT[row*264 + ib], 16);
        }
#pragma unroll
        for(int ot=0;ot<4;ot++)
#pragma unroll
          for(int mt=0;mt<5;mt++)
            acc[ot][mt] = __builtin_amdgcn_mfma_f32_16x16x32_bf16(a[ot], bfr[mt], acc[ot][mt], 0,0,0);
      }
    }
    __syncthreads();
#pragma unroll
    for(int ot=0;ot<4;ot++){
      int ob = (wv*4+ot)*16 + quad*4;
#pragma unroll
      for(int mt=0;mt<5;mt++){
        int row = mt*16 + lr + 2;
        u16 pk[4];
#pragma unroll
        for(int r=0;r<4;r++) pk[r] = f2bf(fast_tanh(acc[ot][mt][r]));
        __builtin_memcpy(&YT[row*264 + ob], pk, 8);
      }
    }
    __syncthreads();
  }
  if(tid < 160){
    int m = tid >> 1, s = tid & 1;
    float accv = 0.f;
    for(int i = s*128; i < s*128+128; i++){
#pragma unroll
      for(int q=0;q<5;q++) accv += w4l[i*5+q] * bf2f(YT[(m+q)*264 + i]);
    }
    red4[tid] = accv;
  }
  __syncthreads();
  if(tid < MDIM){
    float o = red4[2*tid] + red4[2*tid+1] + ld1<F32>(b4, 0) + mell[tid+2];
    st1<F32>(out, (size_t)bt*MDIM + tid, o);
  }
}
__global__ __launch_bounds__(256) void k_postnet(
    const void* w1, const void* b1, const u16* wf2, const void* b2,
    const u16* wf3, const void* b3, const void* w4, const void* b4,
    void* out, const int* dtf)
{
  if(*dtf) postnet_body<true>(w1,b1,wf2,b2,wf3,b3,w4,b4,out);
  else     postnet_body<false>(w1,b1,wf2,b2,wf3,b3,w4,b4,out);
}

// ================= PERSISTENT PATH (plain launch, no cooperative API) =================

struct AttS { float wsp[256]; float Ws[ADIM]; float vl[ADIM]; float el[T]; float red[256]; };
struct ProjS { float lin[H+E]; float pp[160]; float outl[MDIM]; float p1[PDIM]; };
struct UfS  { float cumh[46]; float Fl[LDIM*31]; float Ul[ADIM*LDIM]; float loc[16*LDIM]; };
struct CtxS { float aw[T]; };
union SmemU { AttS att; ProjS proj; UfS uf; CtxS ctx; };   // ~22.6 KB

// one LSTM output column j: 4 gates x 16 batches (same math as verified legacy k_lstm)
template<bool F32>
__device__ __forceinline__ void lstm_unit(int j,
    const void* __restrict__ wih, const void* __restrict__ whh,
    const void* __restrict__ bih, const void* __restrict__ bhh,
    const float* __restrict__ in_x, const float* __restrict__ in_h,
    float* __restrict__ c_io, float* __restrict__ h_out)
{
  int lane = threadIdx.x & 63;
  int wv = threadIdx.x >> 6;
  float acc[4][4];
#pragma unroll
  for(int g=0;g<4;g++)
#pragma unroll
    for(int bb=0;bb<4;bb++) acc[g][bb]=0.f;
#pragma unroll
  for(int it=0; it<4; it++){
    int k = it*256 + lane*4;
    float xi[4][4];
#pragma unroll
    for(int bb=0;bb<4;bb++) __builtin_memcpy(xi[bb], &in_x[(size_t)(wv*4+bb)*H + k], 16);
#pragma unroll
    for(int g=0;g<4;g++){
      float w[4]; ld4<F32>(wih, ((size_t)(g*H + j))*H + k, w);
#pragma unroll
      for(int bb=0;bb<4;bb++)
        acc[g][bb] += w[0]*xi[bb][0] + w[1]*xi[bb][1] + w[2]*xi[bb][2] + w[3]*xi[bb][3];
    }
  }
#pragma unroll
  for(int it=0; it<4; it++){
    int k = it*256 + lane*4;
    float xi[4][4];
#pragma unroll
    for(int bb=0;bb<4;bb++) __builtin_memcpy(xi[bb], &in_h[(size_t)(wv*4+bb)*H + k], 16);
#pragma unroll
    for(int g=0;g<4;g++){
      float w[4]; ld4<F32>(whh, ((size_t)(g*H + j))*H + k, w);
#pragma unroll
      for(int bb=0;bb<4;bb++)
        acc[g][bb] += w[0]*xi[bb][0] + w[1]*xi[bb][1] + w[2]*xi[bb][2] + w[3]*xi[bb][3];
    }
  }
#pragma unroll
  for(int off=1; off<64; off<<=1){
#pragma unroll
    for(int g=0;g<4;g++)
#pragma unroll
      for(int bb=0;bb<4;bb++)
        acc[g][bb] += __shfl_xor(acc[g][bb], off, 64);
  }
  if(lane == 0){
    float bsum[4];
#pragma unroll
    for(int g=0;g<4;g++) bsum[g] = ld1<F32>(bih, g*H+j) + ld1<F32>(bhh, g*H+j);
#pragma unroll
    for(int bb=0;bb<4;bb++){
      int b = wv*4+bb;
      float zi = acc[0][bb] + bsum[0];
      float zf = acc[1][bb] + bsum[1];
      float zg = acc[2][bb] + bsum[2];
      float zo = acc[3][bb] + bsum[3];
      float ig = fast_sig(zi), fg = fast_sig(zf);
      float gg = fast_tanh(zg), og = fast_sig(zo);
      float c = fg * c_io[(size_t)b*H+j] + ig*gg;
      c_io[(size_t)b*H+j] = c;
      h_out[(size_t)b*H+j] = og * fast_tanh(c);
    }
  }
}

// attention scores + softmax for batch b; writes aw (global) and cum
template<bool F32>
__device__ __forceinline__ void attn_unit(int b,
    const float* __restrict__ h1,
    const float* __restrict__ Vh, const float* __restrict__ Uf,
    float* __restrict__ awg, float* __restrict__ cum,
    const void* __restrict__ attW, const void* __restrict__ attWb,
    const void* __restrict__ attv, AttS& S)
{
  int tid = threadIdx.x;
  {
    int a = tid >> 1, s = tid & 1;
    size_t base = (size_t)a*H + s*512;
    const float* hr = &h1[(size_t)b*H + s*512];
    float acc=0.f;
#pragma unroll 4
    for(int k=0;k<512;k+=4){
      float w[4]; ld4<F32>(attW, base+k, w);
      acc += w[0]*hr[k]+w[1]*hr[k+1]+w[2]*hr[k+2]+w[3]*hr[k+3];
    }
    S.wsp[tid]=acc;
  }
  __syncthreads();
  if(tid < ADIM){ S.Ws[tid] = S.wsp[2*tid]+S.wsp[2*tid+1] + ld1<F32>(attWb, tid); S.vl[tid] = ld1<F32>(attv, tid); }
  __syncthreads();
  for(int tt=tid; tt<T; tt+=256){
    const float* vh = &Vh[((size_t)b*T+tt)*ADIM];
    const float* uf = &Uf[((size_t)b*T+tt)*ADIM];
    float acc=0.f;
#pragma unroll 4
    for(int a=0;a<ADIM;a+=4){
      float v4[4], u4[4];
      __builtin_memcpy(v4, &vh[a], 16);
      __builtin_memcpy(u4, &uf[a], 16);
      acc += S.vl[a+0]*fast_tanh(S.Ws[a+0]+v4[0]+u4[0]);
      acc += S.vl[a+1]*fast_tanh(S.Ws[a+1]+v4[1]+u4[1]);
      acc += S.vl[a+2]*fast_tanh(S.Ws[a+2]+v4[2]+u4[2]);
      acc += S.vl[a+3]*fast_tanh(S.Ws[a+3]+v4[3]+u4[3]);
    }
    S.el[tt]=acc;
  }
  __syncthreads();
  float mx = -1e30f;
  for(int tt=tid; tt<T; tt+=256) mx = fmaxf(mx, S.el[tt]);
  S.red[tid]=mx; __syncthreads();
  for(int s=128;s>0;s>>=1){ if(tid<s) S.red[tid]=fmaxf(S.red[tid],S.red[tid+s]); __syncthreads(); }
  mx = S.red[0]; __syncthreads();
  float sum=0.f;
  for(int tt=tid; tt<T; tt+=256){ float ex=__expf(S.el[tt]-mx); S.el[tt]=ex; sum+=ex; }
  S.red[tid]=sum; __syncthreads();
  for(int s=128;s>0;s>>=1){ if(tid<s) S.red[tid]+=S.red[tid+s]; __syncthreads(); }
  float inv = 1.f/S.red[0];
  __syncthreads();
  for(int tt=tid; tt<T; tt+=256){ float a = S.el[tt]*inv; awg[b*T+tt]=a; cum[b*T+tt] += a; }
}

// proj (mel out) + prenet for batch b; writes out and lstm_in[b][0:256]
template<bool F32>
__device__ __forceinline__ void proj_unit(int b, int t,
    const float* __restrict__ h1, const float* __restrict__ att_r,
    const void* __restrict__ projw, const void* __restrict__ projb,
    const void* __restrict__ pw1, const void* __restrict__ pb1,
    const void* __restrict__ pw2, const void* __restrict__ pb2,
    float* __restrict__ lstm_in, void* __restrict__ outp, ProjS& S)
{
  int tid = threadIdx.x;
  for(int i=tid;i<H;i+=256) S.lin[i] = h1[(size_t)b*H+i];
  for(int i=tid;i<E;i+=256) S.lin[H+i] = att_r[b*E+i];
  __syncthreads();
  if(tid < 160){
    int m = tid >> 1, s = tid & 1;
    size_t base = (size_t)m*1792 + s*896;
    const float* lr = &S.lin[s*896];
    float acc=0.f;
#pragma unroll 4
    for(int k=0;k<896;k+=4){
      float w[4]; ld4<F32>(projw, base+k, w);
      acc += w[0]*lr[k]+w[1]*lr[k+1]+w[2]*lr[k+2]+w[3]*lr[k+3];
    }
    S.pp[tid]=acc;
  }
  __syncthreads();
  if(tid < MDIM){
    float o = S.pp[2*tid]+S.pp[2*tid+1] + ld1<F32>(projb, tid);
    S.outl[tid]=o;
    st1<F32>(outp, ((size_t)b*T + t)*MDIM + tid, o);
  }
  __syncthreads();
  {
    float acc = ld1<F32>(pb1, tid);
#pragma unroll
    for(int k=0;k<MDIM;k+=4){
      float w[4]; ld4<F32>(pw1, (size_t)tid*MDIM+k, w);
      acc += w[0]*S.outl[k]+w[1]*S.outl[k+1]+w[2]*S.outl[k+2]+w[3]*S.outl[k+3];
    }
    S.p1[tid] = fmaxf(acc,0.f);
  }
  __syncthreads();
  {
    float acc = ld1<F32>(pb2, tid);
#pragma unroll 4
    for(int k=0;k<PDIM;k+=4){
      float w[4]; ld4<F32>(pw2, (size_t)tid*PDIM+k, w);
      acc += w[0]*S.p1[k]+w[1]*S.p1[k+1]+w[2]*S.p1[k+2]+w[3]*S.p1[k+3];
    }
    lstm_in[b*H + tid] = fmaxf(acc,0.f);
  }
}

// ctx for (b, 256-col chunk): reads aw, x; writes att_w + lstm_in ctx part
template<bool F32>
__device__ __forceinline__ void ctx_unit(int u,
    const float* __restrict__ awg, const void* __restrict__ x,
    float* __restrict__ att_w, float* __restrict__ lstm_in, float* __restrict__ awl)
{
  int b = u/3, cc = u%3;
  int tid = threadIdx.x;
  for(int i=tid;i<T;i+=256) awl[i] = awg[b*T+i];
  __syncthreads();
  int col = cc*256 + tid;
  float a0 = 0.f;
  const size_t xb = (size_t)b*T*E + col;
#pragma unroll 4
  for(int tt=0; tt<T; tt++) a0 += awl[tt] * ld1<F32>(x, xb + (size_t)tt*E);
  att_w[b*E + col] = a0;
  lstm_in[b*H + PDIM + col] = a0;
}

// Uf for (b, 16-t chunk) using updated cum
template<bool F32>
__device__ __forceinline__ void uf_unit(int idx,
    const float* __restrict__ cum, const void* __restrict__ Fw,
    const void* __restrict__ Uw, float* __restrict__ Uf, UfS& S)
{
  int b = idx / 25, ch = idx % 25, t0 = ch*16;
  int tid = threadIdx.x;
  if(tid < 46){ int g = t0 - 15 + tid; S.cumh[tid] = (g>=0 && g<T) ? cum[b*T+g] : 0.f; }
  for(int i=tid; i<LDIM*31; i+=256) S.Fl[i] = ld1<F32>(Fw, i);
  for(int i=tid; i<ADIM*LDIM; i+=256) S.Ul[i] = ld1<F32>(Uw, i);
  __syncthreads();
  for(int i=tid; i<16*LDIM; i+=256){
    int tl = i >> 5, l = i & 31;
    float s=0.f;
    for(int q=0;q<31;q++) s += S.cumh[tl+q]*S.Fl[l*31+q];
    S.loc[i] = s;
  }
  __syncthreads();
  int tl = tid >> 4, al = tid & 15;
  int t = t0 + tl;
#pragma unroll
  for(int aa=0; aa<8; aa++){
    int a = al*8 + aa;
    float s=0.f;
#pragma unroll
    for(int l=0;l<LDIM;l++) s += S.loc[tl*LDIM+l]*S.Ul[a*LDIM+l];
    Uf[((size_t)b*T + t)*ADIM + a] = s;
  }
}

// two-level device-scope grid barrier (generation-based, reusable).
// Release/acquire fences executed by ALL threads (per-XCD L2 non-coherence, G16).
__device__ __forceinline__ void gbar(unsigned* leaf, unsigned* root, unsigned* gen){
  __threadfence();                       // release: flush this block's writes to coherence point
  __syncthreads();                       // all fences done before arrival
  if(threadIdx.x == 0){
    unsigned g = __hip_atomic_load(gen, __ATOMIC_RELAXED, __HIP_MEMORY_SCOPE_AGENT);
    unsigned l = blockIdx.x & 31u;
    unsigned target = gridDim.x >> 5;    // grid is a multiple of 32
    unsigned r = __hip_atomic_fetch_add(&leaf[l*32u], 1u, __ATOMIC_RELAXED, __HIP_MEMORY_SCOPE_AGENT);
    if(r == target - 1u){
      __hip_atomic_store(&leaf[l*32u], 0u, __ATOMIC_RELAXED, __HIP_MEMORY_SCOPE_AGENT);
      unsigned rr = __hip_atomic_fetch_add(root, 1u, __ATOMIC_RELAXED, __HIP_MEMORY_SCOPE_AGENT);
      if(rr == 31u){
        __hip_atomic_store(root, 0u, __ATOMIC_RELAXED, __HIP_MEMORY_SCOPE_AGENT);
        __hip_atomic_fetch_add(gen, 1u, __ATOMIC_RELEASE, __HIP_MEMORY_SCOPE_AGENT);
      }
    }
    long guard = 0;
    while(__hip_atomic_load(gen, __ATOMIC_RELAXED, __HIP_MEMORY_SCOPE_AGENT) == g){
      __builtin_amdgcn_s_sleep(4);
      if(++guard > (1L<<24)) break;      // hang-safety; structurally unreachable (all blocks co-resident)
    }
  }
  __syncthreads();
  __threadfence();                       // acquire: invalidate stale cached lines
}

struct PP {
  const void *wih0,*whh0,*bih0,*bhh0;
  const void *wih1,*whh1,*bih1,*bhh1;
  const void *attW,*attWb,*attv,*attF,*attU;
  const void *projw,*projb,*pw1,*pb1,*pw2,*pb2;
  const void *x;
  float *Vh,*Uf,*h0a,*h0b,*h1a,*h1b,*c0,*c1,*att0,*att1,*lstm_in,*cum,*aw;
  unsigned *barLeaf,*barRoot,*barGen;
  void *outp;
  const int* dtf;
};

template<bool F32>
__device__ void persist_body(const PP& p){
  __shared__ SmemU sm;
  const int nb = gridDim.x;
  float *h0r=p.h0a, *h0w=p.h0b, *h1r=p.h1a, *h1w=p.h1b, *attr=p.att0, *attw=p.att1;
  for(int t=0; t<T; t++){
    // --- phase A: LSTM layer 0 ---
    for(int j=blockIdx.x; j<H; j+=nb)
      lstm_unit<F32>(j, p.wih0,p.whh0,p.bih0,p.bhh0, p.lstm_in, h0r, p.c0, h0w);
    gbar(p.barLeaf, p.barRoot, p.barGen);
    // --- phase B: LSTM layer 1 ---
    for(int j=blockIdx.x; j<H; j+=nb)
      lstm_unit<F32>(j, p.wih1,p.whh1,p.bih1,p.bhh1, h0w, h1r, p.c1, h1w);
    gbar(p.barLeaf, p.barRoot, p.barGen);
    // --- phase C: attention softmax (16) || proj+prenet (16) ---
    for(int u=blockIdx.x; u<32; u+=nb){
      if(u < 16) attn_unit<F32>(u, h1w, p.Vh, p.Uf, p.aw, p.cum, p.attW, p.attWb, p.attv, sm.att);
      else       proj_unit<F32>(u-16, t, h1w, attr, p.projw,p.projb,p.pw1,p.pb1,p.pw2,p.pb2,
                                p.lstm_in, p.outp, sm.proj);
      __syncthreads();
    }
    gbar(p.barLeaf, p.barRoot, p.barGen);
    // --- phase D: ctx (48) || Uf for t+1 (400) ---
    if(t+1 < T){
      for(int u=blockIdx.x; u<448; u+=nb){
        if(u < 48) ctx_unit<F32>(u, p.aw, p.x, attw, p.lstm_in, sm.ctx.aw);
        else       uf_unit<F32>(u-48, p.cum, p.attF, p.attU, p.Uf, sm.uf);
        __syncthreads();
      }
      gbar(p.barLeaf, p.barRoot, p.barGen);
    }
    // swap ping-pong buffers
    float* tp;
    tp=h0r; h0r=h0w; h0w=tp;
    tp=h1r; h1r=h1w; h1w=tp;
    tp=attr; attr=attw; attw=tp;
  }
}

__global__ __launch_bounds__(256, 2) void k_persist(PP p){
  if(*p.dtf) persist_body<true>(p); else persist_body<false>(p);
}

extern "C" void kernel_launch(void* const* d_in, const int* in_sizes, int n_in,
                              void* d_out, int out_size, void* d_ws, size_t ws_size,
                              hipStream_t stream)
{
  (void)in_sizes; (void)n_in; (void)out_size; (void)ws_size;
  const void* x    = d_in[0];
  const void* pw1  = d_in[1];
  const void* pb1  = d_in[2];
  const void* pw2  = d_in[3];
  const void* pb2  = d_in[4];
  const void* wih0 = d_in[5];
  const void* whh0 = d_in[6];
  const void* bih0 = d_in[7];
  const void* bhh0 = d_in[8];
  const void* wih1 = d_in[9];
  const void* whh1 = d_in[10];
  const void* bih1 = d_in[11];
  const void* bhh1 = d_in[12];
  const void* attW = d_in[13];
  const void* attWb= d_in[14];
  const void* attV = d_in[15];
  const void* attU = d_in[16];
  const void* attF = d_in[17];
  const void* attv = d_in[18];
  const void* projw= d_in[19];
  const void* projb= d_in[20];
  const void* pnw1 = d_in[23];
  const void* pnb1 = d_in[24];
  const void* pnw2 = d_in[25];
  const void* pnb2 = d_in[26];
  const void* pnw3 = d_in[27];
  const void* pnb3 = d_in[28];
  const void* pnw4 = d_in[29];
  const void* pnb4 = d_in[30];

  float* base = (float*)d_ws;
  int* dtf = (int*)d_ws;
  size_t off = 4;                           // slot 0..3: dtype flag
  float* Vh   = base + off; off += (size_t)B*T*ADIM;
  // ---- zeroed region starts here ----
  float* Uf   = base + off; off += (size_t)B*T*ADIM;
  float* h0a  = base + off; off += B*H;
  float* h0b  = base + off; off += B*H;
  float* h1a  = base + off; off += B*H;
  float* h1b  = base + off; off += B*H;
  float* c0   = base + off; off += B*H;
  float* c1   = base + off; off += B*H;
  float* att0 = base + off; off += B*E;
  float* att1 = base + off; off += B*E;
  float* lstm_in = base + off; off += B*H;
  float* cum  = base + off; off += B*T;
  float* aw   = base + off; off += B*T;
  unsigned* bar = (unsigned*)(base + off); off += 1088;  // leaf[32*32] @0, root @1024, gen @1056
  // ---- zeroed region ends here ----
  u16* wf2 = (u16*)(base + off); off += (5*8*16*64*8)/2;
  u16* wf3 = (u16*)(base + off); off += (5*8*16*64*8)/2;

  k_detect<<<1, 256, 0, stream>>>((const uint32_t*)x, dtf);
  int nzero = (B*T*ADIM) + 6*B*H + 2*B*E + B*H + B*T + B*T + 1088;
  k_zero<<<(nzero+255)/256, 256, 0, stream>>>(Uf, nzero);
  k_init_prenet<<<1, 256, 0, stream>>>(pw2, pb1, pb2, lstm_in, dtf);
  k_vh<<<B*T, 128, 0, stream>>>(x, attV, Vh, dtf);
  k_repack<<<640, 64, 0, stream>>>(pnw2, wf2, dtf);
  k_repack<<<640, 64, 0, stream>>>(pnw3, wf3, dtf);

  PP p;
  p.wih0=wih0; p.whh0=whh0; p.bih0=bih0; p.bhh0=bhh0;
  p.wih1=wih1; p.whh1=whh1; p.bih1=bih1; p.bhh1=bhh1;
  p.attW=attW; p.attWb=attWb; p.attv=attv; p.attF=attF; p.attU=attU;
  p.projw=projw; p.projb=projb; p.pw1=pw1; p.pb1=pb1; p.pw2=pw2; p.pb2=pb2;
  p.x=x;
  p.Vh=Vh; p.Uf=Uf; p.h0a=h0a; p.h0b=h0b; p.h1a=h1a; p.h1b=h1b;
  p.c0=c0; p.c1=c1; p.att0=att0; p.att1=att1; p.lstm_in=lstm_in; p.cum=cum; p.aw=aw;
  p.barLeaf=bar; p.barRoot=bar+1024; p.barGen=bar+1056;
  p.outp=d_out; p.dtf=dtf;

  // plain (graph-capturable) launch; co-residency guaranteed structurally:
  // 512 blocks, __launch_bounds__(256,2) -> >=2 blocks/CU occupancy, 256 CUs.
  k_persist<<<NBP, 256, 0, stream>>>(p);

  k_postnet<<<B*T, 256, 0, stream>>>(pnw1, pnb1, wf2, pnb2, wf3, pnb3,
                                     pnw4, pnb4, d_out, dtf);
}

// Round 5
// 108105.457 us; speedup vs baseline: 1.8042x; 1.8042x over previous
//
#include <hip/hip_runtime.h>
#include <stdint.h>
#include <stddef.h>

#define B 16
#define T 400
#define E 768
#define PDIM 256
#define H 1024
#define ADIM 128
#define LDIM 32
#define MDIM 80

#define NBP 256            // persistent grid: 1 block/CU needed; capacity >=2/CU guaranteed
#define NLEAF 16
#define LEAFSZ (NBP/NLEAF) // 16

typedef unsigned short u16;
typedef __attribute__((ext_vector_type(8))) short short8v;
typedef __attribute__((ext_vector_type(4))) float float4v;

__device__ __forceinline__ float bf2f(u16 u){
  union { uint32_t i; float f; } v; v.i = ((uint32_t)u) << 16; return v.f;
}
__device__ __forceinline__ u16 f2bf(float f){
  union { float f; uint32_t i; } v; v.f = f;
  uint32_t x = v.i;
  return (u16)((x + 0x7FFFu + ((x >> 16) & 1u)) >> 16);
}
__device__ __forceinline__ float fast_sig(float x){ return 1.f/(1.f+__expf(-x)); }
__device__ __forceinline__ float fast_tanh(float x){ float e=__expf(2.f*x); return 1.f - 2.f/(e+1.f); }

// --- coherent (agent-scope, cache-bypassing) access for mutable cross-block state ---
__device__ __forceinline__ float cohLoadF(const float* p){
  return __hip_atomic_load(p, __ATOMIC_RELAXED, __HIP_MEMORY_SCOPE_AGENT);
}
__device__ __forceinline__ void cohStoreF(float* p, float v){
  __hip_atomic_store(p, v, __ATOMIC_RELAXED, __HIP_MEMORY_SCOPE_AGENT);
}
__device__ __forceinline__ void cohLoad2(const float* p, float o[2]){
  unsigned long long v = __hip_atomic_load((const unsigned long long*)p,
                                           __ATOMIC_RELAXED, __HIP_MEMORY_SCOPE_AGENT);
  __builtin_memcpy(o, &v, 8);
}
// RMW probe: executes at the coherence point -> guaranteed-fresh read
__device__ __forceinline__ unsigned cohProbe(unsigned* p){
  return __hip_atomic_fetch_add(p, 0u, __ATOMIC_RELAXED, __HIP_MEMORY_SCOPE_AGENT);
}

// compile-time specialized loads (read-only params; normal cached path)
template<bool F32>
__device__ __forceinline__ float ld1(const void* p, size_t i){
  if constexpr(F32){ float v; __builtin_memcpy(&v, (const float*)p + i, 4); return v; }
  else { u16 h; __builtin_memcpy(&h, (const u16*)p + i, 2); return bf2f(h); }
}
template<bool F32>
__device__ __forceinline__ void ld4(const void* p, size_t i, float o[4]){
  if constexpr(F32){ __builtin_memcpy(o, (const float*)p + i, 16); }
  else {
    uint2 u; __builtin_memcpy(&u, (const u16*)p + i, 8);
    o[0]=bf2f((u16)(u.x & 0xffffu)); o[1]=bf2f((u16)(u.x >> 16));
    o[2]=bf2f((u16)(u.y & 0xffffu)); o[3]=bf2f((u16)(u.y >> 16));
  }
}
template<bool F32>
__device__ __forceinline__ void st1(void* p, size_t i, float v){
  if constexpr(F32) ((float*)p)[i] = v; else ((u16*)p)[i] = f2bf(v);
}

// ---------------- dtype detect ----------------
__global__ void k_detect(const uint32_t* __restrict__ x, int* flag){
  uint32_t w = x[threadIdx.x];
  float v = bf2f((u16)(w & 0xffffu));
  int bad = (fabsf(v) < 1e4f) ? 0 : 1;
  __shared__ int s[256];
  s[threadIdx.x] = bad;
  __syncthreads();
  for(int st=128; st>0; st>>=1){ if(threadIdx.x<st) s[threadIdx.x]+=s[threadIdx.x+st]; __syncthreads(); }
  if(threadIdx.x==0) *flag = (s[0] >= 8) ? 1 : 0;
}

__global__ void k_zero(float* p, int n){
  int i = blockIdx.x*256 + threadIdx.x;
  if(i < n) p[i] = 0.f;
}

// ---------------- init prenet ----------------
template<bool F32>
__device__ __forceinline__ void init_prenet_body(const void* w2, const void* b1, const void* b2,
                                                 float* lstm_in){
  __shared__ float p1[PDIM];
  int j = threadIdx.x;
  p1[j] = fmaxf(ld1<F32>(b1, j), 0.f);
  __syncthreads();
  float acc = ld1<F32>(b2, j);
  for(int k=0;k<PDIM;k+=4){
    float w[4]; ld4<F32>(w2, (size_t)j*PDIM+k, w);
    acc += w[0]*p1[k]+w[1]*p1[k+1]+w[2]*p1[k+2]+w[3]*p1[k+3];
  }
  float p2 = fmaxf(acc, 0.f);
  for(int b=0;b<B;b++) lstm_in[b*H + j] = p2;
}
__global__ void k_init_prenet(const void* w2, const void* b1, const void* b2,
                              float* lstm_in, const int* dtf){
  if(*dtf) init_prenet_body<true>(w2,b1,b2,lstm_in);
  else     init_prenet_body<false>(w2,b1,b2,lstm_in);
}

// ---------------- Vh ----------------
template<bool F32>
__device__ __forceinline__ void vh_body(const void* __restrict__ x, const void* __restrict__ Vw,
                                        float* __restrict__ Vh){
  int bt = blockIdx.x;
  __shared__ float xr[E];
  for(int i=threadIdx.x;i<E;i+=128) xr[i] = ld1<F32>(x, (size_t)bt*E + i);
  __syncthreads();
  int a = threadIdx.x;
  float acc = 0.f;
#pragma unroll 4
  for(int k=0;k<E;k+=4){
    float w[4]; ld4<F32>(Vw, (size_t)a*E+k, w);
    acc += w[0]*xr[k]+w[1]*xr[k+1]+w[2]*xr[k+2]+w[3]*xr[k+3];
  }
  Vh[(size_t)bt*ADIM + a] = acc;
}
__global__ void k_vh(const void* __restrict__ x, const void* __restrict__ Vw,
                     float* __restrict__ Vh, const int* dtf){
  if(*dtf) vh_body<true>(x,Vw,Vh); else vh_body<false>(x,Vw,Vh);
}

// ------------- PostNet weight repack -------------
template<bool F32>
__device__ __forceinline__ void repack_body(const void* __restrict__ w, u16* __restrict__ wf){
  int blk = blockIdx.x;
  int ot = blk & 15, ic = (blk >> 4) & 7, kw = blk >> 7;
  int lane = threadIdx.x;
  int o = ot*16 + (lane & 15);
  int i0 = ic*32 + (lane >> 4)*8;
  size_t dst = ((size_t)blk*64 + lane)*8;
#pragma unroll
  for(int jj=0;jj<8;jj++)
    wf[dst+jj] = f2bf(ld1<F32>(w, ((size_t)o*256 + (i0+jj))*5 + kw));
}
__global__ void k_repack(const void* w, u16* wf, const int* dtf){
  if(*dtf) repack_body<true>(w,wf); else repack_body<false>(w,wf);
}

// ------------- fused PostNet (verified) -------------
template<bool F32>
__device__ __forceinline__ void postnet_body(
    const void* __restrict__ w1, const void* __restrict__ b1,
    const u16* __restrict__ wf2, const void* __restrict__ b2,
    const u16* __restrict__ wf3, const void* __restrict__ b3,
    const void* __restrict__ w4, const void* __restrict__ b4,
    void* __restrict__ out)
{
  __shared__ u16 YT[88*264];
  __shared__ float mell[84];
  __shared__ float w4l[256*5];
  __shared__ float red4[160];
  int bt = blockIdx.x;
  int tid = threadIdx.x;
  if(tid < 84) mell[tid] = (tid>=2 && tid<82) ? ld1<F32>(out, (size_t)bt*MDIM + tid-2) : 0.f;
  for(int i=tid;i<256*5;i+=256) w4l[i] = ld1<F32>(w4, i);
  for(int i=tid;i<4*264;i+=256){
    int r = i/264, c = i - r*264;
    int row = (r<2)? r : 80+r;
    YT[row*264 + c] = 0;
  }
  __syncthreads();
  {
    float wr[5];
#pragma unroll
    for(int q=0;q<5;q++) wr[q] = ld1<F32>(w1, tid*5+q);
    float bb = ld1<F32>(b1, tid);
    for(int m=0;m<MDIM;m++){
      float s = bb;
#pragma unroll
      for(int q=0;q<5;q++) s += wr[q]*mell[m+q];
      YT[(m+2)*264 + tid] = f2bf(fast_tanh(s));
    }
  }
  __syncthreads();
  int lane = tid & 63, wv = tid >> 6;
  int lr = lane & 15, quad = lane >> 4;
  const u16* WF[2] = {wf2, wf3};
  const void* BS[2] = {b2, b3};
#pragma unroll 1
  for(int layer=0; layer<2; layer++){
    float4v acc[4][5];
#pragma unroll
    for(int ot=0;ot<4;ot++){
      int ob = (wv*4+ot)*16 + quad*4;
#pragma unroll
      for(int mt=0;mt<5;mt++)
#pragma unroll
        for(int r=0;r<4;r++) acc[ot][mt][r] = ld1<F32>(BS[layer], ob + r);
    }
    const u16* wf = WF[layer];
    for(int kw=0;kw<5;kw++){
      for(int ic=0;ic<8;ic++){
        short8v a[4];
#pragma unroll
        for(int ot=0;ot<4;ot++){
          size_t idx = ((size_t)(kw*128 + ic*16 + (wv*4+ot))*64 + lane)*8;
          __builtin_memcpy(&a[ot], &wf[idx], 16);
        }
        short8v bfr[5];
        int ib = ic*32 + quad*8;
#pragma unroll
        for(int mt=0;mt<5;mt++){
          int row = mt*16 + lr + kw;
          __builtin_memcpy(&bfr[mt], &YT[row*264 + ib], 16);
        }
#pragma unroll
        for(int ot=0;ot<4;ot++)
#pragma unroll
          for(int mt=0;mt<5;mt++)
            acc[ot][mt] = __builtin_amdgcn_mfma_f32_16x16x32_bf16(a[ot], bfr[mt], acc[ot][mt], 0,0,0);
      }
    }
    __syncthreads();
#pragma unroll
    for(int ot=0;ot<4;ot++){
      int ob = (wv*4+ot)*16 + quad*4;
#pragma unroll
      for(int mt=0;mt<5;mt++){
        int row = mt*16 + lr + 2;
        u16 pk[4];
#pragma unroll
        for(int r=0;r<4;r++) pk[r] = f2bf(fast_tanh(acc[ot][mt][r]));
        __builtin_memcpy(&YT[row*264 + ob], pk, 8);
      }
    }
    __syncthreads();
  }
  if(tid < 160){
    int m = tid >> 1, s = tid & 1;
    float accv = 0.f;
    for(int i = s*128; i < s*128+128; i++){
#pragma unroll
      for(int q=0;q<5;q++) accv += w4l[i*5+q] * bf2f(YT[(m+q)*264 + i]);
    }
    red4[tid] = accv;
  }
  __syncthreads();
  if(tid < MDIM){
    float o = red4[2*tid] + red4[2*tid+1] + ld1<F32>(b4, 0) + mell[tid+2];
    st1<F32>(out, (size_t)bt*MDIM + tid, o);
  }
}
__global__ __launch_bounds__(256) void k_postnet(
    const void* w1, const void* b1, const u16* wf2, const void* b2,
    const u16* wf3, const void* b3, const void* w4, const void* b4,
    void* out, const int* dtf)
{
  if(*dtf) postnet_body<true>(w1,b1,wf2,b2,wf3,b3,w4,b4,out);
  else     postnet_body<false>(w1,b1,wf2,b2,wf3,b3,w4,b4,out);
}

// ================= PERSISTENT PATH =================
// Weights/x/Vh: read-only, normal cached loads, never invalidated (L2/LLC-hot all 400 steps).
// Mutable cross-block state: ONLY relaxed agent-scope atomics (bypass stale caches). No fences.

struct LstmS { float sx[B][256]; float sh[B][256]; };   // 32 KB (union max)
struct AttS  { float h1l[H]; float Ws[ADIM]; float vl[ADIM]; float el[T];
               float red[256]; float wsp[256]; };        // ~8.8 KB
struct ProjS { float lin[H+E]; float pp[160]; float outl[MDIM]; float p1[PDIM]; };
struct UfS   { float cumh[61]; float Fl[LDIM*31]; float Ul[ADIM*LDIM]; float loc[31*LDIM]; };
struct CtxS  { float awl[T]; };
union SmemU { LstmS lstm; AttS att; ProjS proj; UfS uf; CtxS ctx; };  // 32 KB < 64 KB limit

// LSTM layer phase: block owns cols {bid + u*256, u=0..3}; c-state in registers (lane0).
template<bool F32>
__device__ __forceinline__ void lstm_phase(
    const void* __restrict__ wih, const void* __restrict__ whh,
    const void* __restrict__ bih, const void* __restrict__ bhh,
    const float* __restrict__ in_x, const float* __restrict__ in_h,
    float* __restrict__ h_out, float (&cr)[4][4], LstmS& S)
{
  int tid = threadIdx.x, lane = tid & 63, wv = tid >> 6;
  int bid = blockIdx.x;
  float acc[4][4][4];
#pragma unroll
  for(int u=0;u<4;u++)
#pragma unroll
    for(int g=0;g<4;g++)
#pragma unroll
      for(int bb=0;bb<4;bb++) acc[u][g][bb]=0.f;

#pragma unroll 1
  for(int qr=0; qr<4; qr++){
    __syncthreads();
#pragma unroll
    for(int i=tid; i<B*128; i+=256){
      int b = i >> 7, kk = (i & 127) << 1;
      size_t gofs = (size_t)b*H + qr*256 + kk;
      float vx[2], vh[2];
      cohLoad2(&in_x[gofs], vx);
      cohLoad2(&in_h[gofs], vh);
      S.sx[b][kk] = vx[0]; S.sx[b][kk+1] = vx[1];
      S.sh[b][kk] = vh[0]; S.sh[b][kk+1] = vh[1];
    }
    __syncthreads();
    int k = lane*4;
    float xi[4][4], hi[4][4];
#pragma unroll
    for(int bb=0;bb<4;bb++){
      __builtin_memcpy(xi[bb], &S.sx[wv*4+bb][k], 16);
      __builtin_memcpy(hi[bb], &S.sh[wv*4+bb][k], 16);
    }
    size_t kofs = (size_t)qr*256 + k;
#pragma unroll
    for(int u=0;u<4;u++){
      int j = bid + u*256;
#pragma unroll
      for(int g=0;g<4;g++){
        float w[4]; ld4<F32>(wih, ((size_t)(g*H + j))*H + kofs, w);
#pragma unroll
        for(int bb=0;bb<4;bb++)
          acc[u][g][bb] += w[0]*xi[bb][0]+w[1]*xi[bb][1]+w[2]*xi[bb][2]+w[3]*xi[bb][3];
        float w2[4]; ld4<F32>(whh, ((size_t)(g*H + j))*H + kofs, w2);
#pragma unroll
        for(int bb=0;bb<4;bb++)
          acc[u][g][bb] += w2[0]*hi[bb][0]+w2[1]*hi[bb][1]+w2[2]*hi[bb][2]+w2[3]*hi[bb][3];
      }
    }
  }
#pragma unroll
  for(int off=1; off<64; off<<=1)
#pragma unroll
    for(int u=0;u<4;u++)
#pragma unroll
      for(int g=0;g<4;g++)
#pragma unroll
        for(int bb=0;bb<4;bb++)
          acc[u][g][bb] += __shfl_xor(acc[u][g][bb], off, 64);
  if(lane == 0){
#pragma unroll
    for(int u=0;u<4;u++){
      int j = bid + u*256;
      float bs[4];
#pragma unroll
      for(int g=0;g<4;g++) bs[g] = ld1<F32>(bih, g*H+j) + ld1<F32>(bhh, g*H+j);
#pragma unroll
      for(int bb=0;bb<4;bb++){
        int b = wv*4+bb;
        float zi = acc[u][0][bb]+bs[0];
        float zf = acc[u][1][bb]+bs[1];
        float zg = acc[u][2][bb]+bs[2];
        float zo = acc[u][3][bb]+bs[3];
        float ig = fast_sig(zi), fg = fast_sig(zf);
        float gg2 = fast_tanh(zg), og = fast_sig(zo);
        float c = fg * cr[u][bb] + ig*gg2;
        cr[u][bb] = c;
        cohStoreF(&h_out[(size_t)b*H + j], og * fast_tanh(c));
      }
    }
  }
}

// attention for batch b
template<bool F32>
__device__ __forceinline__ void attn_unit(int b,
    const float* __restrict__ h1, const float* __restrict__ Vh, const float* __restrict__ Uf,
    float* __restrict__ awg, float* __restrict__ cumg,
    const void* __restrict__ attW, const void* __restrict__ attWb,
    const void* __restrict__ attv, AttS& S)
{
  int tid = threadIdx.x;
  for(int i=tid;i<H;i+=256) S.h1l[i] = cohLoadF(&h1[(size_t)b*H+i]);
  if(tid < ADIM) S.vl[tid] = ld1<F32>(attv, tid);
  __syncthreads();
  {
    int a = tid >> 1, s = tid & 1;
    size_t base = (size_t)a*H + s*512;
    const float* hr = &S.h1l[s*512];
    float acc=0.f;
#pragma unroll 4
    for(int k=0;k<512;k+=4){
      float w[4]; ld4<F32>(attW, base+k, w);
      acc += w[0]*hr[k]+w[1]*hr[k+1]+w[2]*hr[k+2]+w[3]*hr[k+3];
    }
    S.wsp[tid]=acc;
  }
  __syncthreads();
  if(tid < ADIM) S.Ws[tid] = S.wsp[2*tid]+S.wsp[2*tid+1] + ld1<F32>(attWb, tid);
  __syncthreads();
  const float* vhb = &Vh[(size_t)b*T*ADIM];
  const float* ufb = &Uf[(size_t)b*T*ADIM];
  for(int tt=tid; tt<T; tt+=256){
    float acc=0.f;
#pragma unroll 2
    for(int a=0;a<ADIM;a+=4){
      float v4[4]; __builtin_memcpy(v4, &vhb[(size_t)tt*ADIM+a], 16);
      float u4[4];
      cohLoad2(&ufb[(size_t)tt*ADIM+a], u4);
      cohLoad2(&ufb[(size_t)tt*ADIM+a+2], u4+2);
      acc += S.vl[a+0]*fast_tanh(S.Ws[a+0]+v4[0]+u4[0]);
      acc += S.vl[a+1]*fast_tanh(S.Ws[a+1]+v4[1]+u4[1]);
      acc += S.vl[a+2]*fast_tanh(S.Ws[a+2]+v4[2]+u4[2]);
      acc += S.vl[a+3]*fast_tanh(S.Ws[a+3]+v4[3]+u4[3]);
    }
    S.el[tt]=acc;
  }
  __syncthreads();
  float mx = -1e30f;
  for(int tt=tid; tt<T; tt+=256) mx = fmaxf(mx, S.el[tt]);
  S.red[tid]=mx; __syncthreads();
  for(int s=128;s>0;s>>=1){ if(tid<s) S.red[tid]=fmaxf(S.red[tid],S.red[tid+s]); __syncthreads(); }
  mx = S.red[0]; __syncthreads();
  float sum=0.f;
  for(int tt=tid; tt<T; tt+=256){ float ex=__expf(S.el[tt]-mx); S.el[tt]=ex; sum+=ex; }
  S.red[tid]=sum; __syncthreads();
  for(int s=128;s>0;s>>=1){ if(tid<s) S.red[tid]+=S.red[tid+s]; __syncthreads(); }
  float inv = 1.f/S.red[0];
  __syncthreads();
  for(int tt=tid; tt<T; tt+=256){
    float a = S.el[tt]*inv;
    cohStoreF(&awg[b*T+tt], a);
    cohStoreF(&cumg[b*T+tt], cohLoadF(&cumg[b*T+tt]) + a);  // single writer per cum[b]
  }
}

// proj (mel out) + prenet for batch b
template<bool F32>
__device__ __forceinline__ void proj_unit(int b, int t,
    const float* __restrict__ h1, const float* __restrict__ att_r,
    const void* __restrict__ projw, const void* __restrict__ projb,
    const void* __restrict__ pw1, const void* __restrict__ pb1,
    const void* __restrict__ pw2, const void* __restrict__ pb2,
    float* __restrict__ lstm_in, void* __restrict__ outp, ProjS& S)
{
  int tid = threadIdx.x;
  for(int i=tid;i<H;i+=256) S.lin[i] = cohLoadF(&h1[(size_t)b*H+i]);
  for(int i=tid;i<E;i+=256) S.lin[H+i] = cohLoadF(&att_r[b*E+i]);
  __syncthreads();
  if(tid < 160){
    int m = tid >> 1, s = tid & 1;
    size_t base = (size_t)m*1792 + s*896;
    const float* lr = &S.lin[s*896];
    float acc=0.f;
#pragma unroll 4
    for(int k=0;k<896;k+=4){
      float w[4]; ld4<F32>(projw, base+k, w);
      acc += w[0]*lr[k]+w[1]*lr[k+1]+w[2]*lr[k+2]+w[3]*lr[k+3];
    }
    S.pp[tid]=acc;
  }
  __syncthreads();
  if(tid < MDIM){
    float o = S.pp[2*tid]+S.pp[2*tid+1] + ld1<F32>(projb, tid);
    S.outl[tid]=o;
    st1<F32>(outp, ((size_t)b*T + t)*MDIM + tid, o);  // consumed by k_postnet after kernel end
  }
  __syncthreads();
  {
    float acc = ld1<F32>(pb1, tid);
#pragma unroll
    for(int k=0;k<MDIM;k+=4){
      float w[4]; ld4<F32>(pw1, (size_t)tid*MDIM+k, w);
      acc += w[0]*S.outl[k]+w[1]*S.outl[k+1]+w[2]*S.outl[k+2]+w[3]*S.outl[k+3];
    }
    S.p1[tid] = fmaxf(acc,0.f);
  }
  __syncthreads();
  {
    float acc = ld1<F32>(pb2, tid);
#pragma unroll 4
    for(int k=0;k<PDIM;k+=4){
      float w[4]; ld4<F32>(pw2, (size_t)tid*PDIM+k, w);
      acc += w[0]*S.p1[k]+w[1]*S.p1[k+1]+w[2]*S.p1[k+2]+w[3]*S.p1[k+3];
    }
    cohStoreF(&lstm_in[b*H + tid], fmaxf(acc,0.f));
  }
}

// ctx for (b, 256-col chunk)
template<bool F32>
__device__ __forceinline__ void ctx_unit(int u,
    const float* __restrict__ awg, const void* __restrict__ x,
    float* __restrict__ att_w, float* __restrict__ lstm_in, float* __restrict__ awl)
{
  int b = u/3, cc = u%3;
  int tid = threadIdx.x;
  for(int i=tid;i<T;i+=256) awl[i] = cohLoadF(&awg[b*T+i]);
  __syncthreads();
  int col = cc*256 + tid;
  float a0 = 0.f;
  const size_t xb = (size_t)b*T*E + col;
#pragma unroll 4
  for(int tt=0; tt<T; tt++) a0 += awl[tt] * ld1<F32>(x, xb + (size_t)tt*E);
  cohStoreF(&att_w[b*E + col], a0);
  cohStoreF(&lstm_in[b*H + PDIM + col], a0);
}

// Uf for (b, 31-t chunk) for step t+1 from updated cum
template<bool F32>
__device__ __forceinline__ void uf_unit(int idx,
    const float* __restrict__ cumg, const void* __restrict__ Fw,
    const void* __restrict__ Uw, float* __restrict__ Uf, UfS& S)
{
  int b = idx / 13, ch = idx % 13, t0 = ch*31;
  int tid = threadIdx.x;
  if(tid < 61){ int g = t0 - 15 + tid; S.cumh[tid] = (g>=0 && g<T) ? cohLoadF(&cumg[b*T+g]) : 0.f; }
  for(int i=tid; i<LDIM*31; i+=256) S.Fl[i] = ld1<F32>(Fw, i);
  for(int i=tid; i<ADIM*LDIM; i+=256) S.Ul[i] = ld1<F32>(Uw, i);
  __syncthreads();
  for(int i=tid; i<31*LDIM; i+=256){
    int tl = i >> 5, l = i & 31;
    float s=0.f;
    for(int q=0;q<31;q++) s += S.cumh[tl+q]*S.Fl[l*31+q];
    S.loc[i] = s;
  }
  __syncthreads();
  for(int i=tid; i<31*16; i+=256){
    int tl = i >> 4, al = i & 15;
    int t = t0 + tl;
    if(t < T){
#pragma unroll
      for(int aa=0; aa<8; aa++){
        int a = al*8 + aa;
        float s=0.f;
#pragma unroll
        for(int l=0;l<LDIM;l++) s += S.loc[tl*LDIM+l]*S.Ul[a*LDIM+l];
        cohStoreF(&Uf[((size_t)b*T + t)*ADIM + a], s);
      }
    }
  }
}

// Tree grid barrier. Relaxed agent atomics only; spin probes are RMW (fetch_add 0)
// so freshness is guaranteed at the coherence point. Any timeout (~2.5 ms) sets a
// global abort flag; all blocks observe it and exit the kernel within a few ms.
// bar layout (u32): leafCnt[16*32]@0 | leafGen[16*32]@512 | root@1024 | gen@1056 | abort@1072
__device__ __forceinline__ bool gbar(unsigned* bar, unsigned gexp){
  asm volatile("s_waitcnt vmcnt(0) lgkmcnt(0)" ::: "memory");  // coherent stores done
  __syncthreads();
  __shared__ int oks;
  if(threadIdx.x == 0){
    int ok = 1;
    unsigned leaf = blockIdx.x & (NLEAF-1);
    unsigned* lc = bar + leaf*32;
    unsigned* lg = bar + NLEAF*32 + leaf*32;
    unsigned* rc = bar + 2*NLEAF*32;
    unsigned* GG = bar + 2*NLEAF*32 + 32;
    unsigned* AB = bar + 2*NLEAF*32 + 48;
    unsigned pos = __hip_atomic_fetch_add(lc, 1u, __ATOMIC_RELAXED, __HIP_MEMORY_SCOPE_AGENT);
    if(pos == LEAFSZ-1u){
      __hip_atomic_store(lc, 0u, __ATOMIC_RELAXED, __HIP_MEMORY_SCOPE_AGENT);
      unsigned r = __hip_atomic_fetch_add(rc, 1u, __ATOMIC_RELAXED, __HIP_MEMORY_SCOPE_AGENT);
      if(r == NLEAF-1u){
        __hip_atomic_store(rc, 0u, __ATOMIC_RELAXED, __HIP_MEMORY_SCOPE_AGENT);
        __hip_atomic_store(GG, gexp, __ATOMIC_RELAXED, __HIP_MEMORY_SCOPE_AGENT);
      } else {
        int guard=0;
        while(cohProbe(GG) < gexp){
          __builtin_amdgcn_s_sleep(2);
          if((guard & 63) == 63 && cohProbe(AB)){ ok=0; break; }
          if(++guard > (1<<13)){ __hip_atomic_store(AB, 1u, __ATOMIC_RELAXED, __HIP_MEMORY_SCOPE_AGENT); ok=0; break; }
        }
      }
      __hip_atomic_store(lg, gexp, __ATOMIC_RELAXED, __HIP_MEMORY_SCOPE_AGENT);
    } else {
      int guard=0;
      while(cohProbe(lg) < gexp){
        __builtin_amdgcn_s_sleep(2);
        if((guard & 63) == 63 && cohProbe(AB)){ ok=0; break; }
        if(++guard > (1<<13)){ __hip_atomic_store(AB, 1u, __ATOMIC_RELAXED, __HIP_MEMORY_SCOPE_AGENT); ok=0; break; }
      }
    }
    oks = ok;
  }
  __syncthreads();
  return oks != 0;
}

struct PP {
  const void *wih0,*whh0,*bih0,*bhh0;
  const void *wih1,*whh1,*bih1,*bhh1;
  const void *attW,*attWb,*attv,*attF,*attU;
  const void *projw,*projb,*pw1,*pb1,*pw2,*pb2;
  const void *x;
  float *Vh,*Uf,*h0a,*h0b,*h1a,*h1b,*att0,*att1,*lstm_in,*cum,*aw;
  unsigned *bar;
  void *outp;
  const int* dtf;
};

template<bool F32>
__device__ void persist_body(const PP& p){
  __shared__ SmemU sm;
  float cr0[4][4], cr1[4][4];
#pragma unroll
  for(int u=0;u<4;u++)
#pragma unroll
    for(int bb=0;bb<4;bb++){ cr0[u][bb]=0.f; cr1[u][bb]=0.f; }

  float *h0r=p.h0a, *h0w=p.h0b, *h1r=p.h1a, *h1w=p.h1b, *attr=p.att0, *attw=p.att1;
  unsigned gexp = 0;
  int bid = blockIdx.x;
  for(int t=0; t<T; t++){
    // A: LSTM layer 0
    lstm_phase<F32>(p.wih0,p.whh0,p.bih0,p.bhh0, p.lstm_in, h0r, h0w, cr0, sm.lstm);
    if(!gbar(p.bar, ++gexp)) return;
    // B: LSTM layer 1
    lstm_phase<F32>(p.wih1,p.whh1,p.bih1,p.bhh1, h0w, h1r, h1w, cr1, sm.lstm);
    if(!gbar(p.bar, ++gexp)) return;
    // C: attn (blocks 0..15) || proj+prenet (16..31)
    if(bid < 16)
      attn_unit<F32>(bid, h1w, p.Vh, p.Uf, p.aw, p.cum, p.attW, p.attWb, p.attv, sm.att);
    else if(bid < 32)
      proj_unit<F32>(bid-16, t, h1w, attr, p.projw,p.projb,p.pw1,p.pb1,p.pw2,p.pb2,
                     p.lstm_in, p.outp, sm.proj);
    if(!gbar(p.bar, ++gexp)) return;
    // D: ctx (0..47) || Uf for t+1 (48..255)
    if(t+1 < T){
      if(bid < 48) ctx_unit<F32>(bid, p.aw, p.x, attw, p.lstm_in, sm.ctx.awl);
      else         uf_unit<F32>(bid-48, p.cum, p.attF, p.attU, p.Uf, sm.uf);
      if(!gbar(p.bar, ++gexp)) return;
    }
    float* tp;
    tp=h0r; h0r=h0w; h0w=tp;
    tp=h1r; h1r=h1w; h1w=tp;
    tp=attr; attr=attw; attw=tp;
  }
}

__global__ __launch_bounds__(256, 2) void k_persist(PP p){
  if(*p.dtf) persist_body<true>(p); else persist_body<false>(p);
}

extern "C" void kernel_launch(void* const* d_in, const int* in_sizes, int n_in,
                              void* d_out, int out_size, void* d_ws, size_t ws_size,
                              hipStream_t stream)
{
  (void)in_sizes; (void)n_in; (void)out_size; (void)ws_size;
  const void* x    = d_in[0];
  const void* pw1  = d_in[1];
  const void* pb1  = d_in[2];
  const void* pw2  = d_in[3];
  const void* pb2  = d_in[4];
  const void* wih0 = d_in[5];
  const void* whh0 = d_in[6];
  const void* bih0 = d_in[7];
  const void* bhh0 = d_in[8];
  const void* wih1 = d_in[9];
  const void* whh1 = d_in[10];
  const void* bih1 = d_in[11];
  const void* bhh1 = d_in[12];
  const void* attW = d_in[13];
  const void* attWb= d_in[14];
  const void* attV = d_in[15];
  const void* attU = d_in[16];
  const void* attF = d_in[17];
  const void* attv = d_in[18];
  const void* projw= d_in[19];
  const void* projb= d_in[20];
  const void* pnw1 = d_in[23];
  const void* pnb1 = d_in[24];
  const void* pnw2 = d_in[25];
  const void* pnb2 = d_in[26];
  const void* pnw3 = d_in[27];
  const void* pnb3 = d_in[28];
  const void* pnw4 = d_in[29];
  const void* pnb4 = d_in[30];

  float* base = (float*)d_ws;
  int* dtf = (int*)d_ws;
  size_t off = 4;
  float* Vh   = base + off; off += (size_t)B*T*ADIM;
  // ---- zeroed region (re-zeroed every replay; includes barrier + abort flag) ----
  float* Uf   = base + off; off += (size_t)B*T*ADIM;
  float* h0a  = base + off; off += B*H;
  float* h0b  = base + off; off += B*H;
  float* h1a  = base + off; off += B*H;
  float* h1b  = base + off; off += B*H;
  float* att0 = base + off; off += B*E;
  float* att1 = base + off; off += B*E;
  float* lstm_in = base + off; off += B*H;
  float* cum  = base + off; off += B*T;
  float* aw   = base + off; off += B*T;
  unsigned* bar = (unsigned*)(base + off); off += 1088;
  // ---- zeroed region ends ----
  u16* wf2 = (u16*)(base + off); off += (5*8*16*64*8)/2;
  u16* wf3 = (u16*)(base + off); off += (5*8*16*64*8)/2;

  k_detect<<<1, 256, 0, stream>>>((const uint32_t*)x, dtf);
  int nzero = (B*T*ADIM) + 4*B*H + 2*B*E + B*H + 2*B*T + 1088;
  k_zero<<<(nzero+255)/256, 256, 0, stream>>>(Uf, nzero);
  k_init_prenet<<<1, 256, 0, stream>>>(pw2, pb1, pb2, lstm_in, dtf);
  k_vh<<<B*T, 128, 0, stream>>>(x, attV, Vh, dtf);
  k_repack<<<640, 64, 0, stream>>>(pnw2, wf2, dtf);
  k_repack<<<640, 64, 0, stream>>>(pnw3, wf3, dtf);

  PP p;
  p.wih0=wih0; p.whh0=whh0; p.bih0=bih0; p.bhh0=bhh0;
  p.wih1=wih1; p.whh1=whh1; p.bih1=bih1; p.bhh1=bhh1;
  p.attW=attW; p.attWb=attWb; p.attv=attv; p.attF=attF; p.attU=attU;
  p.projw=projw; p.projb=projb; p.pw1=pw1; p.pb1=pb1; p.pw2=pw2; p.pb2=pb2;
  p.x=x;
  p.Vh=Vh; p.Uf=Uf; p.h0a=h0a; p.h0b=h0b; p.h1a=h1a; p.h1b=h1b;
  p.att0=att0; p.att1=att1; p.lstm_in=lstm_in; p.cum=cum; p.aw=aw;
  p.bar=bar; p.outp=d_out; p.dtf=dtf;

  // 256 blocks on 256 CUs; co-residency needs 1 block/CU (capacity 2: 32 KB LDS,
  // launch_bounds(256,2) VGPR<=256). Plain, graph-capturable launch.
  k_persist<<<NBP, 256, 0, stream>>>(p);

  k_postnet<<<B*T, 256, 0, stream>>>(pnw1, pnb1, wf2, pnb2, wf3, pnb3,
                                     pnw4, pnb4, d_out, dtf);
}

// Round 6
// 107369.836 us; speedup vs baseline: 1.8166x; 1.0069x over previous
//
#include <hip/hip_runtime.h>
#include <stdint.h>
#include <stddef.h>

#define B 16
#define T 400
#define E 768
#define PDIM 256
#define H 1024
#define ADIM 128
#define LDIM 32
#define MDIM 80

#define NBP 256            // persistent grid: 1 block/CU needed; capacity >=2/CU guaranteed
#define NLEAF 16
#define LEAFSZ (NBP/NLEAF) // 16

typedef unsigned short u16;
typedef __attribute__((ext_vector_type(8))) short short8v;
typedef __attribute__((ext_vector_type(4))) float float4v;

__device__ __forceinline__ float bf2f(u16 u){
  union { uint32_t i; float f; } v; v.i = ((uint32_t)u) << 16; return v.f;
}
__device__ __forceinline__ u16 f2bf(float f){
  union { float f; uint32_t i; } v; v.f = f;
  uint32_t x = v.i;
  return (u16)((x + 0x7FFFu + ((x >> 16) & 1u)) >> 16);
}
__device__ __forceinline__ float fast_sig(float x){ return 1.f/(1.f+__expf(-x)); }
__device__ __forceinline__ float fast_tanh(float x){ float e=__expf(2.f*x); return 1.f - 2.f/(e+1.f); }

// --- coherent (agent-scope, cache-bypassing) access for mutable cross-block state ---
__device__ __forceinline__ float cohLoadF(const float* p){
  return __hip_atomic_load(p, __ATOMIC_RELAXED, __HIP_MEMORY_SCOPE_AGENT);
}
__device__ __forceinline__ void cohStoreF(float* p, float v){
  __hip_atomic_store(p, v, __ATOMIC_RELAXED, __HIP_MEMORY_SCOPE_AGENT);
}
// RMW probe: executes at the coherence point -> guaranteed-fresh read
__device__ __forceinline__ unsigned cohProbe(unsigned* p){
  return __hip_atomic_fetch_add(p, 0u, __ATOMIC_RELAXED, __HIP_MEMORY_SCOPE_AGENT);
}
// Batched uncached 16B loads: issue many, then one wait. sc0 sc1 = bypass L1+L2.
__device__ __forceinline__ void cohIssue4(const float* p, float4v& d){
  asm volatile("global_load_dwordx4 %0, %1, off sc0 sc1" : "=v"(d) : "v"(p));
}
__device__ __forceinline__ void cohWaitAll(){
  asm volatile("s_waitcnt vmcnt(0)" ::: "memory");
  __builtin_amdgcn_sched_barrier(0);   // keep uses after the wait (r263/r282 pattern)
}

// compile-time specialized loads (read-only params; normal cached path)
template<bool F32>
__device__ __forceinline__ float ld1(const void* p, size_t i){
  if constexpr(F32){ float v; __builtin_memcpy(&v, (const float*)p + i, 4); return v; }
  else { u16 h; __builtin_memcpy(&h, (const u16*)p + i, 2); return bf2f(h); }
}
template<bool F32>
__device__ __forceinline__ void ld4(const void* p, size_t i, float o[4]){
  if constexpr(F32){ __builtin_memcpy(o, (const float*)p + i, 16); }
  else {
    uint2 u; __builtin_memcpy(&u, (const u16*)p + i, 8);
    o[0]=bf2f((u16)(u.x & 0xffffu)); o[1]=bf2f((u16)(u.x >> 16));
    o[2]=bf2f((u16)(u.y & 0xffffu)); o[3]=bf2f((u16)(u.y >> 16));
  }
}
template<bool F32>
__device__ __forceinline__ void st1(void* p, size_t i, float v){
  if constexpr(F32) ((float*)p)[i] = v; else ((u16*)p)[i] = f2bf(v);
}

// ---------------- dtype detect ----------------
__global__ void k_detect(const uint32_t* __restrict__ x, int* flag){
  uint32_t w = x[threadIdx.x];
  float v = bf2f((u16)(w & 0xffffu));
  int bad = (fabsf(v) < 1e4f) ? 0 : 1;
  __shared__ int s[256];
  s[threadIdx.x] = bad;
  __syncthreads();
  for(int st=128; st>0; st>>=1){ if(threadIdx.x<st) s[threadIdx.x]+=s[threadIdx.x+st]; __syncthreads(); }
  if(threadIdx.x==0) *flag = (s[0] >= 8) ? 1 : 0;
}

__global__ void k_zero(float* p, int n){
  int i = blockIdx.x*256 + threadIdx.x;
  if(i < n) p[i] = 0.f;
}

// ---------------- init prenet ----------------
template<bool F32>
__device__ __forceinline__ void init_prenet_body(const void* w2, const void* b1, const void* b2,
                                                 float* lstm_in){
  __shared__ float p1[PDIM];
  int j = threadIdx.x;
  p1[j] = fmaxf(ld1<F32>(b1, j), 0.f);
  __syncthreads();
  float acc = ld1<F32>(b2, j);
  for(int k=0;k<PDIM;k+=4){
    float w[4]; ld4<F32>(w2, (size_t)j*PDIM+k, w);
    acc += w[0]*p1[k]+w[1]*p1[k+1]+w[2]*p1[k+2]+w[3]*p1[k+3];
  }
  float p2 = fmaxf(acc, 0.f);
  for(int b=0;b<B;b++) lstm_in[b*H + j] = p2;
}
__global__ void k_init_prenet(const void* w2, const void* b1, const void* b2,
                              float* lstm_in, const int* dtf){
  if(*dtf) init_prenet_body<true>(w2,b1,b2,lstm_in);
  else     init_prenet_body<false>(w2,b1,b2,lstm_in);
}

// ---------------- Vh ----------------
template<bool F32>
__device__ __forceinline__ void vh_body(const void* __restrict__ x, const void* __restrict__ Vw,
                                        float* __restrict__ Vh){
  int bt = blockIdx.x;
  __shared__ float xr[E];
  for(int i=threadIdx.x;i<E;i+=128) xr[i] = ld1<F32>(x, (size_t)bt*E + i);
  __syncthreads();
  int a = threadIdx.x;
  float acc = 0.f;
#pragma unroll 4
  for(int k=0;k<E;k+=4){
    float w[4]; ld4<F32>(Vw, (size_t)a*E+k, w);
    acc += w[0]*xr[k]+w[1]*xr[k+1]+w[2]*xr[k+2]+w[3]*xr[k+3];
  }
  Vh[(size_t)bt*ADIM + a] = acc;
}
__global__ void k_vh(const void* __restrict__ x, const void* __restrict__ Vw,
                     float* __restrict__ Vh, const int* dtf){
  if(*dtf) vh_body<true>(x,Vw,Vh); else vh_body<false>(x,Vw,Vh);
}

// ------------- PostNet weight repack -------------
template<bool F32>
__device__ __forceinline__ void repack_body(const void* __restrict__ w, u16* __restrict__ wf){
  int blk = blockIdx.x;
  int ot = blk & 15, ic = (blk >> 4) & 7, kw = blk >> 7;
  int lane = threadIdx.x;
  int o = ot*16 + (lane & 15);
  int i0 = ic*32 + (lane >> 4)*8;
  size_t dst = ((size_t)blk*64 + lane)*8;
#pragma unroll
  for(int jj=0;jj<8;jj++)
    wf[dst+jj] = f2bf(ld1<F32>(w, ((size_t)o*256 + (i0+jj))*5 + kw));
}
__global__ void k_repack(const void* w, u16* wf, const int* dtf){
  if(*dtf) repack_body<true>(w,wf); else repack_body<false>(w,wf);
}

// ------------- fused PostNet (verified) -------------
template<bool F32>
__device__ __forceinline__ void postnet_body(
    const void* __restrict__ w1, const void* __restrict__ b1,
    const u16* __restrict__ wf2, const void* __restrict__ b2,
    const u16* __restrict__ wf3, const void* __restrict__ b3,
    const void* __restrict__ w4, const void* __restrict__ b4,
    void* __restrict__ out)
{
  __shared__ u16 YT[88*264];
  __shared__ float mell[84];
  __shared__ float w4l[256*5];
  __shared__ float red4[160];
  int bt = blockIdx.x;
  int tid = threadIdx.x;
  if(tid < 84) mell[tid] = (tid>=2 && tid<82) ? ld1<F32>(out, (size_t)bt*MDIM + tid-2) : 0.f;
  for(int i=tid;i<256*5;i+=256) w4l[i] = ld1<F32>(w4, i);
  for(int i=tid;i<4*264;i+=256){
    int r = i/264, c = i - r*264;
    int row = (r<2)? r : 80+r;
    YT[row*264 + c] = 0;
  }
  __syncthreads();
  {
    float wr[5];
#pragma unroll
    for(int q=0;q<5;q++) wr[q] = ld1<F32>(w1, tid*5+q);
    float bb = ld1<F32>(b1, tid);
    for(int m=0;m<MDIM;m++){
      float s = bb;
#pragma unroll
      for(int q=0;q<5;q++) s += wr[q]*mell[m+q];
      YT[(m+2)*264 + tid] = f2bf(fast_tanh(s));
    }
  }
  __syncthreads();
  int lane = tid & 63, wv = tid >> 6;
  int lr = lane & 15, quad = lane >> 4;
  const u16* WF[2] = {wf2, wf3};
  const void* BS[2] = {b2, b3};
#pragma unroll 1
  for(int layer=0; layer<2; layer++){
    float4v acc[4][5];
#pragma unroll
    for(int ot=0;ot<4;ot++){
      int ob = (wv*4+ot)*16 + quad*4;
#pragma unroll
      for(int mt=0;mt<5;mt++)
#pragma unroll
        for(int r=0;r<4;r++) acc[ot][mt][r] = ld1<F32>(BS[layer], ob + r);
    }
    const u16* wf = WF[layer];
    for(int kw=0;kw<5;kw++){
      for(int ic=0;ic<8;ic++){
        short8v a[4];
#pragma unroll
        for(int ot=0;ot<4;ot++){
          size_t idx = ((size_t)(kw*128 + ic*16 + (wv*4+ot))*64 + lane)*8;
          __builtin_memcpy(&a[ot], &wf[idx], 16);
        }
        short8v bfr[5];
        int ib = ic*32 + quad*8;
#pragma unroll
        for(int mt=0;mt<5;mt++){
          int row = mt*16 + lr + kw;
          __builtin_memcpy(&bfr[mt], &YT[row*264 + ib], 16);
        }
#pragma unroll
        for(int ot=0;ot<4;ot++)
#pragma unroll
          for(int mt=0;mt<5;mt++)
            acc[ot][mt] = __builtin_amdgcn_mfma_f32_16x16x32_bf16(a[ot], bfr[mt], acc[ot][mt], 0,0,0);
      }
    }
    __syncthreads();
#pragma unroll
    for(int ot=0;ot<4;ot++){
      int ob = (wv*4+ot)*16 + quad*4;
#pragma unroll
      for(int mt=0;mt<5;mt++){
        int row = mt*16 + lr + 2;
        u16 pk[4];
#pragma unroll
        for(int r=0;r<4;r++) pk[r] = f2bf(fast_tanh(acc[ot][mt][r]));
        __builtin_memcpy(&YT[row*264 + ob], pk, 8);
      }
    }
    __syncthreads();
  }
  if(tid < 160){
    int m = tid >> 1, s = tid & 1;
    float accv = 0.f;
    for(int i = s*128; i < s*128+128; i++){
#pragma unroll
      for(int q=0;q<5;q++) accv += w4l[i*5+q] * bf2f(YT[(m+q)*264 + i]);
    }
    red4[tid] = accv;
  }
  __syncthreads();
  if(tid < MDIM){
    float o = red4[2*tid] + red4[2*tid+1] + ld1<F32>(b4, 0) + mell[tid+2];
    st1<F32>(out, (size_t)bt*MDIM + tid, o);
  }
}
__global__ __launch_bounds__(256) void k_postnet(
    const void* w1, const void* b1, const u16* wf2, const void* b2,
    const u16* wf3, const void* b3, const void* w4, const void* b4,
    void* out, const int* dtf)
{
  if(*dtf) postnet_body<true>(w1,b1,wf2,b2,wf3,b3,w4,b4,out);
  else     postnet_body<false>(w1,b1,wf2,b2,wf3,b3,w4,b4,out);
}

// ================= PERSISTENT PATH =================
// Weights/x/Vh: read-only, normal cached loads, never invalidated (L2/LLC path).
// Mutable cross-block state: uncached agent-scope accesses only. No fences anywhere.
// All uncached reads are BATCHED dwordx4 (deep vmcnt pipeline) -> latency amortized.

struct LstmS { float sx[B][256]; float sh[B][256]; };   // 32 KB (union max)
struct AttS  { float h1l[H]; float Ws[ADIM]; float vl[ADIM]; float el[T];
               float red[256]; float wsp[256]; };
struct ProjS { float lin[H+E]; float pp[160]; float outl[MDIM]; float p1[PDIM]; };
struct UfS   { float cumh[61]; float Fl[LDIM*31]; float Ul[ADIM*LDIM]; float loc[31*LDIM]; };
struct CtxS  { float awl[T]; };
union SmemU { LstmS lstm; AttS att; ProjS proj; UfS uf; CtxS ctx; };  // 32 KB < 64 KB limit

// LSTM layer phase: block owns cols {bid + u*256, u=0..3}; c-state in registers (lane0).
// Inputs staged into LDS in 256-wide quarters: 8 uncached dwordx4 in flight per thread.
template<bool F32>
__device__ __forceinline__ void lstm_phase(
    const void* __restrict__ wih, const void* __restrict__ whh,
    const void* __restrict__ bih, const void* __restrict__ bhh,
    const float* __restrict__ in_x, const float* __restrict__ in_h,
    float* __restrict__ h_out, float (&cr)[4][4], LstmS& S)
{
  int tid = threadIdx.x, lane = tid & 63, wv = tid >> 6;
  int bid = blockIdx.x;
  int sb = tid >> 4, skb = (tid & 15) << 4;   // staging: thread covers 16 floats of (b=sb)
  float acc[4][4][4];
#pragma unroll
  for(int u=0;u<4;u++)
#pragma unroll
    for(int g=0;g<4;g++)
#pragma unroll
      for(int bb=0;bb<4;bb++) acc[u][g][bb]=0.f;

#pragma unroll 1
  for(int qr=0; qr<4; qr++){
    __syncthreads();
    {
      const float* px = &in_x[(size_t)sb*H + qr*256 + skb];
      const float* ph = &in_h[(size_t)sb*H + qr*256 + skb];
      float4v rx0,rx1,rx2,rx3, rh0,rh1,rh2,rh3;
      cohIssue4(px+0,  rx0); cohIssue4(px+4,  rx1);
      cohIssue4(px+8,  rx2); cohIssue4(px+12, rx3);
      cohIssue4(ph+0,  rh0); cohIssue4(ph+4,  rh1);
      cohIssue4(ph+8,  rh2); cohIssue4(ph+12, rh3);
      cohWaitAll();
      __builtin_memcpy(&S.sx[sb][skb+0],  &rx0, 16);
      __builtin_memcpy(&S.sx[sb][skb+4],  &rx1, 16);
      __builtin_memcpy(&S.sx[sb][skb+8],  &rx2, 16);
      __builtin_memcpy(&S.sx[sb][skb+12], &rx3, 16);
      __builtin_memcpy(&S.sh[sb][skb+0],  &rh0, 16);
      __builtin_memcpy(&S.sh[sb][skb+4],  &rh1, 16);
      __builtin_memcpy(&S.sh[sb][skb+8],  &rh2, 16);
      __builtin_memcpy(&S.sh[sb][skb+12], &rh3, 16);
    }
    __syncthreads();
    int k = lane*4;
    float xi[4][4], hi[4][4];
#pragma unroll
    for(int bb=0;bb<4;bb++){
      __builtin_memcpy(xi[bb], &S.sx[wv*4+bb][k], 16);
      __builtin_memcpy(hi[bb], &S.sh[wv*4+bb][k], 16);
    }
    size_t kofs = (size_t)qr*256 + k;
#pragma unroll
    for(int u=0;u<4;u++){
      int j = bid + u*256;
#pragma unroll
      for(int g=0;g<4;g++){
        float w[4]; ld4<F32>(wih, ((size_t)(g*H + j))*H + kofs, w);
#pragma unroll
        for(int bb=0;bb<4;bb++)
          acc[u][g][bb] += w[0]*xi[bb][0]+w[1]*xi[bb][1]+w[2]*xi[bb][2]+w[3]*xi[bb][3];
        float w2[4]; ld4<F32>(whh, ((size_t)(g*H + j))*H + kofs, w2);
#pragma unroll
        for(int bb=0;bb<4;bb++)
          acc[u][g][bb] += w2[0]*hi[bb][0]+w2[1]*hi[bb][1]+w2[2]*hi[bb][2]+w2[3]*hi[bb][3];
      }
    }
  }
#pragma unroll
  for(int off=1; off<64; off<<=1)
#pragma unroll
    for(int u=0;u<4;u++)
#pragma unroll
      for(int g=0;g<4;g++)
#pragma unroll
        for(int bb=0;bb<4;bb++)
          acc[u][g][bb] += __shfl_xor(acc[u][g][bb], off, 64);
  if(lane == 0){
#pragma unroll
    for(int u=0;u<4;u++){
      int j = bid + u*256;
      float bs[4];
#pragma unroll
      for(int g=0;g<4;g++) bs[g] = ld1<F32>(bih, g*H+j) + ld1<F32>(bhh, g*H+j);
#pragma unroll
      for(int bb=0;bb<4;bb++){
        int b = wv*4+bb;
        float zi = acc[u][0][bb]+bs[0];
        float zf = acc[u][1][bb]+bs[1];
        float zg = acc[u][2][bb]+bs[2];
        float zo = acc[u][3][bb]+bs[3];
        float ig = fast_sig(zi), fg = fast_sig(zf);
        float gg2 = fast_tanh(zg), og = fast_sig(zo);
        float c = fg * cr[u][bb] + ig*gg2;
        cr[u][bb] = c;
        cohStoreF(&h_out[(size_t)b*H + j], og * fast_tanh(c));
      }
    }
  }
}

// attention for batch b; Uf rows read as two 16-deep dwordx4 batches
template<bool F32>
__device__ __forceinline__ void attn_unit(int b,
    const float* __restrict__ h1, const float* __restrict__ Vh, const float* __restrict__ Uf,
    float* __restrict__ awg, float* __restrict__ cumg,
    const void* __restrict__ attW, const void* __restrict__ attWb,
    const void* __restrict__ attv, AttS& S)
{
  int tid = threadIdx.x;
  {
    float4v r; cohIssue4(&h1[(size_t)b*H + tid*4], r);
    cohWaitAll();
    __builtin_memcpy(&S.h1l[tid*4], &r, 16);
  }
  if(tid < ADIM) S.vl[tid] = ld1<F32>(attv, tid);
  __syncthreads();
  {
    int a = tid >> 1, s = tid & 1;
    size_t base = (size_t)a*H + s*512;
    const float* hr = &S.h1l[s*512];
    float acc=0.f;
#pragma unroll 4
    for(int k=0;k<512;k+=4){
      float w[4]; ld4<F32>(attW, base+k, w);
      acc += w[0]*hr[k]+w[1]*hr[k+1]+w[2]*hr[k+2]+w[3]*hr[k+3];
    }
    S.wsp[tid]=acc;
  }
  __syncthreads();
  if(tid < ADIM) S.Ws[tid] = S.wsp[2*tid]+S.wsp[2*tid+1] + ld1<F32>(attWb, tid);
  __syncthreads();
  const float* vhb = &Vh[(size_t)b*T*ADIM];
  const float* ufb = &Uf[(size_t)b*T*ADIM];
  for(int tt=tid; tt<T; tt+=256){
    const float* ufr = &ufb[(size_t)tt*ADIM];
    const float* vhr = &vhb[(size_t)tt*ADIM];
    float acc=0.f;
#pragma unroll 1
    for(int hh=0; hh<2; hh++){
      float4v uu[16];
#pragma unroll
      for(int i=0;i<16;i++) cohIssue4(ufr + hh*64 + i*4, uu[i]);
      cohWaitAll();
#pragma unroll
      for(int i=0;i<16;i++){
        int a = hh*64 + i*4;
        float v4[4]; __builtin_memcpy(v4, &vhr[a], 16);
        acc += S.vl[a+0]*fast_tanh(S.Ws[a+0]+v4[0]+uu[i][0]);
        acc += S.vl[a+1]*fast_tanh(S.Ws[a+1]+v4[1]+uu[i][1]);
        acc += S.vl[a+2]*fast_tanh(S.Ws[a+2]+v4[2]+uu[i][2]);
        acc += S.vl[a+3]*fast_tanh(S.Ws[a+3]+v4[3]+uu[i][3]);
      }
    }
    S.el[tt]=acc;
  }
  __syncthreads();
  float mx = -1e30f;
  for(int tt=tid; tt<T; tt+=256) mx = fmaxf(mx, S.el[tt]);
  S.red[tid]=mx; __syncthreads();
  for(int s=128;s>0;s>>=1){ if(tid<s) S.red[tid]=fmaxf(S.red[tid],S.red[tid+s]); __syncthreads(); }
  mx = S.red[0]; __syncthreads();
  float sum=0.f;
  for(int tt=tid; tt<T; tt+=256){ float ex=__expf(S.el[tt]-mx); S.el[tt]=ex; sum+=ex; }
  S.red[tid]=sum; __syncthreads();
  for(int s=128;s>0;s>>=1){ if(tid<s) S.red[tid]+=S.red[tid+s]; __syncthreads(); }
  float inv = 1.f/S.red[0];
  __syncthreads();
  for(int tt=tid; tt<T; tt+=256){
    float a = S.el[tt]*inv;
    cohStoreF(&awg[b*T+tt], a);
    cohStoreF(&cumg[b*T+tt], cohLoadF(&cumg[b*T+tt]) + a);  // single writer per cum[b]
  }
}

// proj (mel out) + prenet for batch b
template<bool F32>
__device__ __forceinline__ void proj_unit(int b, int t,
    const float* __restrict__ h1, const float* __restrict__ att_r,
    const void* __restrict__ projw, const void* __restrict__ projb,
    const void* __restrict__ pw1, const void* __restrict__ pb1,
    const void* __restrict__ pw2, const void* __restrict__ pb2,
    float* __restrict__ lstm_in, void* __restrict__ outp, ProjS& S)
{
  int tid = threadIdx.x;
  {
    float4v r0; cohIssue4(&h1[(size_t)b*H + tid*4], r0);
    float4v r1;
    if(tid < 192) cohIssue4(&att_r[(size_t)b*E + tid*4], r1);
    cohWaitAll();
    __builtin_memcpy(&S.lin[tid*4], &r0, 16);
    if(tid < 192) __builtin_memcpy(&S.lin[H + tid*4], &r1, 16);
  }
  __syncthreads();
  if(tid < 160){
    int m = tid >> 1, s = tid & 1;
    size_t base = (size_t)m*1792 + s*896;
    const float* lr = &S.lin[s*896];
    float acc=0.f;
#pragma unroll 4
    for(int k=0;k<896;k+=4){
      float w[4]; ld4<F32>(projw, base+k, w);
      acc += w[0]*lr[k]+w[1]*lr[k+1]+w[2]*lr[k+2]+w[3]*lr[k+3];
    }
    S.pp[tid]=acc;
  }
  __syncthreads();
  if(tid < MDIM){
    float o = S.pp[2*tid]+S.pp[2*tid+1] + ld1<F32>(projb, tid);
    S.outl[tid]=o;
    st1<F32>(outp, ((size_t)b*T + t)*MDIM + tid, o);  // consumed by k_postnet after kernel end
  }
  __syncthreads();
  {
    float acc = ld1<F32>(pb1, tid);
#pragma unroll
    for(int k=0;k<MDIM;k+=4){
      float w[4]; ld4<F32>(pw1, (size_t)tid*MDIM+k, w);
      acc += w[0]*S.outl[k]+w[1]*S.outl[k+1]+w[2]*S.outl[k+2]+w[3]*S.outl[k+3];
    }
    S.p1[tid] = fmaxf(acc,0.f);
  }
  __syncthreads();
  {
    float acc = ld1<F32>(pb2, tid);
#pragma unroll 4
    for(int k=0;k<PDIM;k+=4){
      float w[4]; ld4<F32>(pw2, (size_t)tid*PDIM+k, w);
      acc += w[0]*S.p1[k]+w[1]*S.p1[k+1]+w[2]*S.p1[k+2]+w[3]*S.p1[k+3];
    }
    cohStoreF(&lstm_in[b*H + tid], fmaxf(acc,0.f));
  }
}

// ctx for (b, 256-col chunk)
template<bool F32>
__device__ __forceinline__ void ctx_unit(int u,
    const float* __restrict__ awg, const void* __restrict__ x,
    float* __restrict__ att_w, float* __restrict__ lstm_in, float* __restrict__ awl)
{
  int b = u/3, cc = u%3;
  int tid = threadIdx.x;
  {
    float4v r;
    if(tid < 100) cohIssue4(&awg[(size_t)b*T + tid*4], r);
    cohWaitAll();
    if(tid < 100) __builtin_memcpy(&awl[tid*4], &r, 16);
  }
  __syncthreads();
  int col = cc*256 + tid;
  float a0 = 0.f;
  const size_t xb = (size_t)b*T*E + col;
#pragma unroll 4
  for(int tt=0; tt<T; tt++) a0 += awl[tt] * ld1<F32>(x, xb + (size_t)tt*E);
  cohStoreF(&att_w[b*E + col], a0);
  cohStoreF(&lstm_in[b*H + PDIM + col], a0);
}

// Uf for (b, 31-t chunk) for step t+1 from updated cum
template<bool F32>
__device__ __forceinline__ void uf_unit(int idx,
    const float* __restrict__ cumg, const void* __restrict__ Fw,
    const void* __restrict__ Uw, float* __restrict__ Uf, UfS& S)
{
  int b = idx / 13, ch = idx % 13, t0 = ch*31;
  int tid = threadIdx.x;
  if(tid < 61){ int g = t0 - 15 + tid; S.cumh[tid] = (g>=0 && g<T) ? cohLoadF(&cumg[b*T+g]) : 0.f; }
  for(int i=tid; i<LDIM*31; i+=256) S.Fl[i] = ld1<F32>(Fw, i);
  for(int i=tid; i<ADIM*LDIM; i+=256) S.Ul[i] = ld1<F32>(Uw, i);
  __syncthreads();
  for(int i=tid; i<31*LDIM; i+=256){
    int tl = i >> 5, l = i & 31;
    float s=0.f;
    for(int q=0;q<31;q++) s += S.cumh[tl+q]*S.Fl[l*31+q];
    S.loc[i] = s;
  }
  __syncthreads();
  for(int i=tid; i<31*16; i+=256){
    int tl = i >> 4, al = i & 15;
    int t = t0 + tl;
    if(t < T){
#pragma unroll
      for(int aa=0; aa<8; aa++){
        int a = al*8 + aa;
        float s=0.f;
#pragma unroll
        for(int l=0;l<LDIM;l++) s += S.loc[tl*LDIM+l]*S.Ul[a*LDIM+l];
        cohStoreF(&Uf[((size_t)b*T + t)*ADIM + a], s);
      }
    }
  }
}

// Tree grid barrier (unchanged from verified R5): relaxed agent atomics, RMW probes,
// ~2.5 ms timeout -> global abort -> fast clean exit. No cache-invalidating fences.
__device__ __forceinline__ bool gbar(unsigned* bar, unsigned gexp){
  asm volatile("s_waitcnt vmcnt(0) lgkmcnt(0)" ::: "memory");  // coherent stores done
  __syncthreads();
  __shared__ int oks;
  if(threadIdx.x == 0){
    int ok = 1;
    unsigned leaf = blockIdx.x & (NLEAF-1);
    unsigned* lc = bar + leaf*32;
    unsigned* lg = bar + NLEAF*32 + leaf*32;
    unsigned* rc = bar + 2*NLEAF*32;
    unsigned* GG = bar + 2*NLEAF*32 + 32;
    unsigned* AB = bar + 2*NLEAF*32 + 48;
    unsigned pos = __hip_atomic_fetch_add(lc, 1u, __ATOMIC_RELAXED, __HIP_MEMORY_SCOPE_AGENT);
    if(pos == LEAFSZ-1u){
      __hip_atomic_store(lc, 0u, __ATOMIC_RELAXED, __HIP_MEMORY_SCOPE_AGENT);
      unsigned r = __hip_atomic_fetch_add(rc, 1u, __ATOMIC_RELAXED, __HIP_MEMORY_SCOPE_AGENT);
      if(r == NLEAF-1u){
        __hip_atomic_store(rc, 0u, __ATOMIC_RELAXED, __HIP_MEMORY_SCOPE_AGENT);
        __hip_atomic_store(GG, gexp, __ATOMIC_RELAXED, __HIP_MEMORY_SCOPE_AGENT);
      } else {
        int guard=0;
        while(cohProbe(GG) < gexp){
          __builtin_amdgcn_s_sleep(2);
          if((guard & 63) == 63 && cohProbe(AB)){ ok=0; break; }
          if(++guard > (1<<13)){ __hip_atomic_store(AB, 1u, __ATOMIC_RELAXED, __HIP_MEMORY_SCOPE_AGENT); ok=0; break; }
        }
      }
      __hip_atomic_store(lg, gexp, __ATOMIC_RELAXED, __HIP_MEMORY_SCOPE_AGENT);
    } else {
      int guard=0;
      while(cohProbe(lg) < gexp){
        __builtin_amdgcn_s_sleep(2);
        if((guard & 63) == 63 && cohProbe(AB)){ ok=0; break; }
        if(++guard > (1<<13)){ __hip_atomic_store(AB, 1u, __ATOMIC_RELAXED, __HIP_MEMORY_SCOPE_AGENT); ok=0; break; }
      }
    }
    oks = ok;
  }
  __syncthreads();
  return oks != 0;
}

struct PP {
  const void *wih0,*whh0,*bih0,*bhh0;
  const void *wih1,*whh1,*bih1,*bhh1;
  const void *attW,*attWb,*attv,*attF,*attU;
  const void *projw,*projb,*pw1,*pb1,*pw2,*pb2;
  const void *x;
  float *Vh,*Uf,*h0a,*h0b,*h1a,*h1b,*att0,*att1,*lstm_in,*cum,*aw;
  unsigned *bar;
  void *outp;
  const int* dtf;
};

template<bool F32>
__device__ void persist_body(const PP& p){
  __shared__ SmemU sm;
  float cr0[4][4], cr1[4][4];
#pragma unroll
  for(int u=0;u<4;u++)
#pragma unroll
    for(int bb=0;bb<4;bb++){ cr0[u][bb]=0.f; cr1[u][bb]=0.f; }

  float *h0r=p.h0a, *h0w=p.h0b, *h1r=p.h1a, *h1w=p.h1b, *attr=p.att0, *attw=p.att1;
  unsigned gexp = 0;
  int bid = blockIdx.x;
  for(int t=0; t<T; t++){
    // A: LSTM layer 0
    lstm_phase<F32>(p.wih0,p.whh0,p.bih0,p.bhh0, p.lstm_in, h0r, h0w, cr0, sm.lstm);
    if(!gbar(p.bar, ++gexp)) return;
    // B: LSTM layer 1
    lstm_phase<F32>(p.wih1,p.whh1,p.bih1,p.bhh1, h0w, h1r, h1w, cr1, sm.lstm);
    if(!gbar(p.bar, ++gexp)) return;
    // C: attn (blocks 0..15) || proj+prenet (16..31)
    if(bid < 16)
      attn_unit<F32>(bid, h1w, p.Vh, p.Uf, p.aw, p.cum, p.attW, p.attWb, p.attv, sm.att);
    else if(bid < 32)
      proj_unit<F32>(bid-16, t, h1w, attr, p.projw,p.projb,p.pw1,p.pb1,p.pw2,p.pb2,
                     p.lstm_in, p.outp, sm.proj);
    if(!gbar(p.bar, ++gexp)) return;
    // D: ctx (0..47) || Uf for t+1 (48..255)
    if(t+1 < T){
      if(bid < 48) ctx_unit<F32>(bid, p.aw, p.x, attw, p.lstm_in, sm.ctx.awl);
      else         uf_unit<F32>(bid-48, p.cum, p.attF, p.attU, p.Uf, sm.uf);
      if(!gbar(p.bar, ++gexp)) return;
    }
    float* tp;
    tp=h0r; h0r=h0w; h0w=tp;
    tp=h1r; h1r=h1w; h1w=tp;
    tp=attr; attr=attw; attw=tp;
  }
}

__global__ __launch_bounds__(256, 2) void k_persist(PP p){
  if(*p.dtf) persist_body<true>(p); else persist_body<false>(p);
}

extern "C" void kernel_launch(void* const* d_in, const int* in_sizes, int n_in,
                              void* d_out, int out_size, void* d_ws, size_t ws_size,
                              hipStream_t stream)
{
  (void)in_sizes; (void)n_in; (void)out_size; (void)ws_size;
  const void* x    = d_in[0];
  const void* pw1  = d_in[1];
  const void* pb1  = d_in[2];
  const void* pw2  = d_in[3];
  const void* pb2  = d_in[4];
  const void* wih0 = d_in[5];
  const void* whh0 = d_in[6];
  const void* bih0 = d_in[7];
  const void* bhh0 = d_in[8];
  const void* wih1 = d_in[9];
  const void* whh1 = d_in[10];
  const void* bih1 = d_in[11];
  const void* bhh1 = d_in[12];
  const void* attW = d_in[13];
  const void* attWb= d_in[14];
  const void* attV = d_in[15];
  const void* attU = d_in[16];
  const void* attF = d_in[17];
  const void* attv = d_in[18];
  const void* projw= d_in[19];
  const void* projb= d_in[20];
  const void* pnw1 = d_in[23];
  const void* pnb1 = d_in[24];
  const void* pnw2 = d_in[25];
  const void* pnb2 = d_in[26];
  const void* pnw3 = d_in[27];
  const void* pnb3 = d_in[28];
  const void* pnw4 = d_in[29];
  const void* pnb4 = d_in[30];

  float* base = (float*)d_ws;
  int* dtf = (int*)d_ws;
  size_t off = 4;
  float* Vh   = base + off; off += (size_t)B*T*ADIM;
  // ---- zeroed region (re-zeroed every replay; includes barrier + abort flag) ----
  float* Uf   = base + off; off += (size_t)B*T*ADIM;
  float* h0a  = base + off; off += B*H;
  float* h0b  = base + off; off += B*H;
  float* h1a  = base + off; off += B*H;
  float* h1b  = base + off; off += B*H;
  float* att0 = base + off; off += B*E;
  float* att1 = base + off; off += B*E;
  float* lstm_in = base + off; off += B*H;
  float* cum  = base + off; off += B*T;
  float* aw   = base + off; off += B*T;
  unsigned* bar = (unsigned*)(base + off); off += 1088;
  // ---- zeroed region ends ----
  u16* wf2 = (u16*)(base + off); off += (5*8*16*64*8)/2;
  u16* wf3 = (u16*)(base + off); off += (5*8*16*64*8)/2;

  k_detect<<<1, 256, 0, stream>>>((const uint32_t*)x, dtf);
  int nzero = (B*T*ADIM) + 4*B*H + 2*B*E + B*H + 2*B*T + 1088;
  k_zero<<<(nzero+255)/256, 256, 0, stream>>>(Uf, nzero);
  k_init_prenet<<<1, 256, 0, stream>>>(pw2, pb1, pb2, lstm_in, dtf);
  k_vh<<<B*T, 128, 0, stream>>>(x, attV, Vh, dtf);
  k_repack<<<640, 64, 0, stream>>>(pnw2, wf2, dtf);
  k_repack<<<640, 64, 0, stream>>>(pnw3, wf3, dtf);

  PP p;
  p.wih0=wih0; p.whh0=whh0; p.bih0=bih0; p.bhh0=bhh0;
  p.wih1=wih1; p.whh1=whh1; p.bih1=bih1; p.bhh1=bhh1;
  p.attW=attW; p.attWb=attWb; p.attv=attv; p.attF=attF; p.attU=attU;
  p.projw=projw; p.projb=projb; p.pw1=pw1; p.pb1=pb1; p.pw2=pw2; p.pb2=pb2;
  p.x=x;
  p.Vh=Vh; p.Uf=Uf; p.h0a=h0a; p.h0b=h0b; p.h1a=h1a; p.h1b=h1b;
  p.att0=att0; p.att1=att1; p.lstm_in=lstm_in; p.cum=cum; p.aw=aw;
  p.bar=bar; p.outp=d_out; p.dtf=dtf;

  // 256 blocks on 256 CUs; co-residency needs 1 block/CU (capacity 2: 32 KB LDS,
  // launch_bounds(256,2) VGPR<=256). Plain, graph-capturable launch.
  k_persist<<<NBP, 256, 0, stream>>>(p);

  k_postnet<<<B*T, 256, 0, stream>>>(pnw1, pnb1, wf2, pnb2, wf3, pnb3,
                                     pnw4, pnb4, d_out, dtf);
}